// Round 7
// baseline (323.446 us; speedup 1.0000x reference)
//
#include <hip/hip_runtime.h>
#include <math.h>

#define NPT 8192
#define HWIMG 19200
#define KCAP 128

using short8 = __attribute__((ext_vector_type(8))) short;
using f32x4  = __attribute__((ext_vector_type(4))) float;

__device__ __forceinline__ float lrelu(float x) { return x > 0.f ? x : 0.01f * x; }
__device__ __forceinline__ unsigned short f2bf(float v) {
  unsigned u = __float_as_uint(v);
  return (unsigned short)((u + 0x7fffu + ((u >> 16) & 1u)) >> 16);
}
__device__ __forceinline__ float bf2f(unsigned short h) {
  return __uint_as_float(((unsigned)h) << 16);
}
__device__ __forceinline__ void split2(float v, unsigned short& h, unsigned short& l) {
  h = f2bf(v);
  l = f2bf(v - bf2f(h));
}
// split-bf16 3-term MFMA: acc += Ah*Wh + Al*Wh + Ah*Wl  (~1e-5 rel accuracy)
__device__ __forceinline__ void mfma3(f32x4& acc, short8 ah, short8 al, short8 wh, short8 wl) {
  acc = __builtin_amdgcn_mfma_f32_16x16x32_bf16(ah, wh, acc, 0, 0, 0);
  acc = __builtin_amdgcn_mfma_f32_16x16x32_bf16(al, wh, acc, 0, 0, 0);
  acc = __builtin_amdgcn_mfma_f32_16x16x32_bf16(ah, wl, acc, 0, 0, 0);
}

// weight-plane segment offsets (in shorts)
#define OFF_PCONV2  0
#define OFF_CONV1   8192
#define OFF_CONV2   10240
#define OFF_PSCONV1 18432
#define OFF_PSCONV2 51200
#define OFF_FINAL   83968
#define OFF_W3      137216
#define OFF_W2P     186368

// mega-kernel prep-rest segment sizes
#define PR_W3    49152
#define PR_BIASC 128
#define PR_W2P   8192
#define PR_B2C   64
#define PR_FEAT  (NPT*32)
#define PR_WSPL  OFF_W3
#define PREP_REST (PR_W3 + PR_BIASC + PR_W2P + PR_B2C + PR_FEAT + PR_WSPL)  // 456896
#define MEGA_GRID (2049 + (PREP_REST + 255)/256)   // 2049 + 1785 = 3834

// ---------------- prep0: c4 pack + g/counter zero (tiny) -----------------------
__global__ void k_prep0(const float* __restrict__ cloud, float* __restrict__ c4,
                        float* __restrict__ g) {
  int i = blockIdx.x * blockDim.x + threadIdx.x;
  if (i < NPT) {
    float x = cloud[i*3+0], y = cloud[i*3+1], z = cloud[i*3+2];
    float4 v; v.x = x; v.y = y; v.z = z; v.w = x*x + y*y + z*z;
    ((float4*)c4)[i] = v;
  }
  int j = i - NPT;
  if (j >= 0 && j < 129) g[j] = 0.f;
}

// ---------------- bitonic helpers ---------------------------------------------
__device__ __forceinline__ unsigned long long bsort64(unsigned long long key, int lane) {
#pragma unroll
  for (int k = 2; k <= 64; k <<= 1) {
#pragma unroll
    for (int j = k >> 1; j > 0; j >>= 1) {
      unsigned long long o = __shfl_xor(key, j, 64);
      bool keepmin = (((lane & j) == 0) == ((lane & k) == 0));
      bool omin = o < key;
      key = (omin == keepmin) ? o : key;
    }
  }
  return key;
}
__device__ __forceinline__ unsigned long long bmerge64(unsigned long long key, int lane) {
#pragma unroll
  for (int j = 32; j > 0; j >>= 1) {
    unsigned long long o = __shfl_xor(key, j, 64);
    bool keepmin = ((lane & j) == 0);
    bool omin = o < key;
    key = (omin == keepmin) ? o : key;
  }
  return key;
}

// ---------------- mega: knn (blocks 0..2047) | dc (2048) | prep-rest (2049+) ---
__global__ __launch_bounds__(256) void k_mega(const float4* __restrict__ c4,
                                              int* __restrict__ idxo, float* __restrict__ wo,
                                              const float* __restrict__ cloud,
                                              const float* __restrict__ tvec,
                                              float* __restrict__ dc,
                                              const int* __restrict__ choose,
                                              const float* __restrict__ img,
                                              const float* __restrict__ seg1_w, const float* __restrict__ dis1_w,
                                              const float* __restrict__ seg1_b, const float* __restrict__ dis1_b,
                                              const float* __restrict__ seg2_w, const float* __restrict__ dis2_w,
                                              const float* __restrict__ seg2_b, const float* __restrict__ dis2_b,
                                              const float* __restrict__ pconv2_w, const float* __restrict__ conv1_w,
                                              const float* __restrict__ conv2_w, const float* __restrict__ psconv1_w,
                                              const float* __restrict__ psconv2_w, const float* __restrict__ final_w,
                                              float* __restrict__ biasc, float* __restrict__ bias2c,
                                              float* __restrict__ feat,
                                              unsigned short* __restrict__ feat_h,
                                              unsigned short* __restrict__ feat_l,
                                              unsigned short* __restrict__ Wh,
                                              unsigned short* __restrict__ Wl) {
  int tid = threadIdx.x, lane = tid & 63, wv = tid >> 6;
  if (blockIdx.x > 2048) {
    // ---- prep-rest: feat gather+split, weight transposes/splits, bias tables --
    int j = (blockIdx.x - 2049) * 256 + tid;
    if (j < PR_W3) {                       // conv3 weight transpose + split
      int h = j / 24576, r = j - h*24576, o = r / 384, k = r - o*384;
      int t = k >> 7, c = k & 127;
      float v = (h ? dis1_w : seg1_w)[o*384 + c*3 + t];
      unsigned short hh, ll; split2(v, hh, ll);
      Wh[OFF_W3 + j] = hh; Wl[OFF_W3 + j] = ll;
      return;
    }
    j -= PR_W3;
    if (j < PR_BIASC) { biasc[j] = (j < 64) ? seg1_b[j] : dis1_b[j-64]; return; }
    j -= PR_BIASC;
    if (j < PR_W2P) {                      // W2p block-diagonal + split
      int o = j >> 7, c = j & 127;
      float v = 0.f;
      if (o < 32) { if (c < 64) v = seg2_w[o*64 + c]; }
      else        { if (c >= 64) v = dis2_w[(o-32)*64 + (c-64)]; }
      unsigned short hh, ll; split2(v, hh, ll);
      Wh[OFF_W2P + j] = hh; Wl[OFF_W2P + j] = ll;
      return;
    }
    j -= PR_W2P;
    if (j < PR_B2C) { bias2c[j] = (j < 32) ? seg2_b[j] : dis2_b[j-32]; return; }
    j -= PR_B2C;
    if (j < PR_FEAT) {                     // feat gather + split
      int n = j >> 5, ch = j & 31;
      float v = img[ch*HWIMG + choose[n]];
      feat[j] = v;
      unsigned short hh, ll; split2(v, hh, ll);
      feat_h[j] = hh; feat_l[j] = ll;
      return;
    }
    j -= PR_FEAT;
    if (j < PR_WSPL) {                     // weight split
      float v;
      if      (j < OFF_CONV1)   v = pconv2_w[j];
      else if (j < OFF_CONV2)   v = conv1_w[j - OFF_CONV1];
      else if (j < OFF_PSCONV1) v = conv2_w[j - OFF_CONV2];
      else if (j < OFF_PSCONV2) v = psconv1_w[j - OFF_PSCONV1];
      else if (j < OFF_FINAL)   v = psconv2_w[j - OFF_PSCONV2];
      else                      v = final_w[j - OFF_FINAL];
      unsigned short hh, ll; split2(v, hh, ll);
      Wh[j] = hh; Wl[j] = ll;
    }
    return;
  }
  if (blockIdx.x == 2048) {
    // ---- dis_center softmax ----
    __shared__ float sred[4];
    float tx = tvec[0], ty = tvec[1], tz = tvec[2];
    float v[32];
    float m = -INFINITY;
#pragma unroll
    for (int i2 = 0; i2 < 32; ++i2) {
      int n = i2*256 + tid;
      float ax = cloud[n*3+0] + tx, ay = cloud[n*3+1] + ty, az = cloud[n*3+2] + tz;
      v[i2] = sqrtf(ax*ax + ay*ay + az*az);
      m = fmaxf(m, v[i2]);
    }
#pragma unroll
    for (int o = 1; o < 64; o <<= 1) m = fmaxf(m, __shfl_xor(m, o, 64));
    if (lane == 0) sred[wv] = m;
    __syncthreads();
    m = fmaxf(fmaxf(sred[0], sred[1]), fmaxf(sred[2], sred[3]));
    __syncthreads();
    float s = 0.f;
#pragma unroll
    for (int i2 = 0; i2 < 32; ++i2) { v[i2] = expf(v[i2] - m); s += v[i2]; }
#pragma unroll
    for (int o = 1; o < 64; o <<= 1) s += __shfl_xor(s, o, 64);
    if (lane == 0) sred[wv] = s;
    __syncthreads();
    s = sred[0] + sred[1] + sred[2] + sred[3];
#pragma unroll
    for (int i2 = 0; i2 < 32; ++i2) dc[i2*256 + tid] = v[i2] / s;
    return;
  }
  // ---- knn: 4 queries/block, dot-form prune, exact select ----
  __shared__ float smin[4][256];
  __shared__ float sT[4];
  __shared__ float sd[4][KCAP];
  __shared__ int   sj[4][KCAP];
  __shared__ int   scnt[4];
  int q0 = blockIdx.x * 4;
  float4 p0 = c4[q0], p1 = c4[q0+1], p2 = c4[q0+2], p3 = c4[q0+3];
  float p0x = -2.f*p0.x, p0y = -2.f*p0.y, p0z = -2.f*p0.z;
  float p1x = -2.f*p1.x, p1y = -2.f*p1.y, p1z = -2.f*p1.z;
  float p2x = -2.f*p2.x, p2y = -2.f*p2.y, p2z = -2.f*p2.z;
  float p3x = -2.f*p3.x, p3y = -2.f*p3.y, p3z = -2.f*p3.z;
#define DDOT(PX,PY,PZ,PW,CJ) fmaf(PX,(CJ).x, fmaf(PY,(CJ).y, fmaf(PZ,(CJ).z, PW + (CJ).w)))
  float m0 = INFINITY, m1 = INFINITY, m2 = INFINITY, m3 = INFINITY;
  for (int t = 0; t < 32; ++t) {
    float4 cj = c4[t*256 + tid];
    m0 = fminf(m0, DDOT(p0x,p0y,p0z,p0.w,cj));
    m1 = fminf(m1, DDOT(p1x,p1y,p1z,p1.w,cj));
    m2 = fminf(m2, DDOT(p2x,p2y,p2z,p2.w,cj));
    m3 = fminf(m3, DDOT(p3x,p3y,p3z,p3.w,cj));
  }
  smin[0][tid] = m0; smin[1][tid] = m1; smin[2][tid] = m2; smin[3][tid] = m3;
  if (tid < 4) scnt[tid] = 0;
  __syncthreads();
  {
    float4 vv = *(const float4*)&smin[wv][lane*4];
    float v0 = vv.x, v1 = vv.y, v2 = vv.z, v3 = vv.w;
#define CSV(a,b) { if (b < a) { float t_ = a; a = b; b = t_; } }
    CSV(v0,v2) CSV(v1,v3) CSV(v0,v1) CSV(v2,v3) CSV(v1,v2)
    float T = 0.f;
    for (int it = 0; it < 32; ++it) {
      float mn = v0;
#pragma unroll
      for (int o = 1; o < 64; o <<= 1) mn = fminf(mn, __shfl_xor(mn, o, 64));
      T = mn;
      if (v0 == mn) { v0 = v1; v1 = v2; v2 = v3; v3 = INFINITY; }
    }
    if (lane == 0) sT[wv] = T * (1.f + 2e-5f) + 4e-5f;
  }
  __syncthreads();
  float T0 = sT[0], T1 = sT[1], T2 = sT[2], T3 = sT[3];
  for (int t = 0; t < 32; ++t) {
    int j = t*256 + tid;
    float4 cj = c4[j];
    float d;
#define APPEND(Q, P) { \
    float dx_ = (P).x-cj.x, dy_ = (P).y-cj.y, dz_ = (P).z-cj.z; \
    float de_ = dx_*dx_ + dy_*dy_ + dz_*dz_; \
    int p_ = atomicAdd(&scnt[Q],1); if (p_ < KCAP) { sd[Q][p_] = de_; sj[Q][p_] = j; } }
    d = DDOT(p0x,p0y,p0z,p0.w,cj); if (d <= T0) APPEND(0, p0);
    d = DDOT(p1x,p1y,p1z,p1.w,cj); if (d <= T1) APPEND(1, p1);
    d = DDOT(p2x,p2y,p2z,p2.w,cj); if (d <= T2) APPEND(2, p2);
    d = DDOT(p3x,p3y,p3z,p3.w,cj); if (d <= T3) APPEND(3, p3);
  }
  __syncthreads();
  int M = scnt[wv]; if (M > KCAP) M = KCAP;
  unsigned long long key = (lane < M)
      ? (((unsigned long long)__float_as_uint(sd[wv][lane]) << 32) | (unsigned)sj[wv][lane])
      : ~0ull;
  key = bsort64(key, lane);
  for (int base = 64; base < M; base += 64) {
    unsigned long long nk = (base + lane < M)
        ? (((unsigned long long)__float_as_uint(sd[wv][base+lane]) << 32) | (unsigned)sj[wv][base+lane])
        : ~0ull;
    nk = bsort64(nk, lane);
    nk = __shfl_xor(nk, 63, 64);
    key = key < nk ? key : nk;
    key = bmerge64(key, lane);
  }
  float dsel = __uint_as_float((unsigned)(key >> 32));
  int   jsel = (int)(unsigned)(key & 0xffffffffu);
  float v = -sqrtf(dsel);
  float mx = v;
#pragma unroll
  for (int o = 1; o < 32; o <<= 1) mx = fmaxf(mx, __shfl_xor(mx, o, 64));
  float e = expf(v - mx);
  float s = e;
#pragma unroll
  for (int o = 1; o < 32; o <<= 1) s += __shfl_xor(s, o, 64);
  if (lane < 32) {
    int q = q0 + wv;
    wo[q*32 + lane] = e / s;
    idxo[q*32 + lane] = jsel;
  }
}

// ---------------- fused MLP chains: 4 waves share one 16-row m-tile, t-split ---
__global__ __launch_bounds__(256) void k_chain(const float4* __restrict__ c4,
                                              const float* __restrict__ pconv1_w, const float* __restrict__ pconv1_b,
                                              const float* __restrict__ pconv2_b, const float* __restrict__ psconv1_b,
                                              const float* __restrict__ psconv2_b,
                                              const unsigned short* __restrict__ feat_h,
                                              const unsigned short* __restrict__ feat_l,
                                              const float* __restrict__ conv1_b, const float* __restrict__ conv2_b,
                                              const unsigned short* __restrict__ Wh,
                                              const unsigned short* __restrict__ Wl,
                                              float* __restrict__ pf, float* __restrict__ Yfp,
                                              float* __restrict__ Yf) {
  __shared__ unsigned short sh_h[6400], sh_l[6400];
  int tid = threadIdx.x, lane = tid & 63, w = tid >> 6;
  int mr = lane & 15, q = lane >> 4;
  if (blockIdx.x < 512) {
    int m0 = blockIdx.x * 16;
    float4 cp = c4[m0 + mr];
    short8 ah0, al0, ah1, al1;
#pragma unroll
    for (int j = 0; j < 8; ++j) {
      int c0 = q*8 + j, c1 = 32 + q*8 + j;
      float v0 = lrelu(fmaf(cp.x, pconv1_w[c0*3+0], fmaf(cp.y, pconv1_w[c0*3+1],
                        fmaf(cp.z, pconv1_w[c0*3+2], pconv1_b[c0]))));
      float v1 = lrelu(fmaf(cp.x, pconv1_w[c1*3+0], fmaf(cp.y, pconv1_w[c1*3+1],
                        fmaf(cp.z, pconv1_w[c1*3+2], pconv1_b[c1]))));
      unsigned short hh, ll;
      split2(v0, hh, ll); ah0[j] = (short)hh; al0[j] = (short)ll;
      split2(v1, hh, ll); ah1[j] = (short)hh; al1[j] = (short)ll;
    }
    f32x4 acc[2];
#pragma unroll
    for (int t = 0; t < 2; ++t) { f32x4 z = {0.f,0.f,0.f,0.f}; acc[t] = z; }
    const unsigned short* W2h = Wh + OFF_PCONV2;
    const unsigned short* W2l = Wl + OFF_PCONV2;
#pragma unroll
    for (int tt = 0; tt < 2; ++tt) {
      int wr = ((2*w+tt)*16 + mr)*64 + q*8;
      mfma3(acc[tt], ah0, al0, *(const short8*)(W2h + wr), *(const short8*)(W2l + wr));
      mfma3(acc[tt], ah1, al1, *(const short8*)(W2h + wr + 32), *(const short8*)(W2l + wr + 32));
    }
#pragma unroll
    for (int tt = 0; tt < 2; ++tt) {
      int n = (2*w+tt)*16 + mr;
      float b = pconv2_b[n];
#pragma unroll
      for (int r = 0; r < 4; ++r) {
        int row = q*4 + r;
        float v = acc[tt][r] + b;
        pf[(size_t)(m0+row)*128 + n] = v;
        unsigned short hh, ll; split2(v, hh, ll);
        sh_h[row*136 + n] = hh; sh_l[row*136 + n] = ll;
      }
    }
    __syncthreads();
    f32x4 acc2[4];
#pragma unroll
    for (int t = 0; t < 4; ++t) { f32x4 z = {0.f,0.f,0.f,0.f}; acc2[t] = z; }
    const unsigned short* W3h = Wh + OFF_PSCONV1;
    const unsigned short* W3l = Wl + OFF_PSCONV1;
#pragma unroll
    for (int ks = 0; ks < 4; ++ks) {
      short8 ah = *(const short8*)&sh_h[mr*136 + q*8 + ks*32];
      short8 al = *(const short8*)&sh_l[mr*136 + q*8 + ks*32];
#pragma unroll
      for (int tt = 0; tt < 4; ++tt) {
        int wr = ((4*w+tt)*16 + mr)*128 + q*8 + ks*32;
        mfma3(acc2[tt], ah, al, *(const short8*)(W3h + wr), *(const short8*)(W3l + wr));
      }
    }
#pragma unroll
    for (int tt = 0; tt < 4; ++tt) {
      int n = (4*w+tt)*16 + mr;
      float b = psconv1_b[n];
#pragma unroll
      for (int r = 0; r < 4; ++r) {
        int row = q*4 + r;
        float v = lrelu(acc2[tt][r] + b);
        unsigned short hh, ll; split2(v, hh, ll);
        sh_h[2176 + row*264 + n] = hh; sh_l[2176 + row*264 + n] = ll;
      }
    }
    __syncthreads();
    f32x4 acc3[2];
#pragma unroll
    for (int t = 0; t < 2; ++t) { f32x4 z = {0.f,0.f,0.f,0.f}; acc3[t] = z; }
    const unsigned short* W4h = Wh + OFF_PSCONV2;
    const unsigned short* W4l = Wl + OFF_PSCONV2;
#pragma unroll
    for (int ks = 0; ks < 8; ++ks) {
      short8 ah = *(const short8*)&sh_h[2176 + mr*264 + q*8 + ks*32];
      short8 al = *(const short8*)&sh_l[2176 + mr*264 + q*8 + ks*32];
#pragma unroll
      for (int tt = 0; tt < 2; ++tt) {
        int wr = ((2*w+tt)*16 + mr)*256 + q*8 + ks*32;
        mfma3(acc3[tt], ah, al, *(const short8*)(W4h + wr), *(const short8*)(W4l + wr));
      }
    }
#pragma unroll
    for (int tt = 0; tt < 2; ++tt) {
      int n = (2*w+tt)*16 + mr;
      float b = psconv2_b[n];
#pragma unroll
      for (int r = 0; r < 4; ++r)
        Yfp[(size_t)(m0 + q*4 + r)*128 + n] = acc3[tt][r] + b;
    }
  } else {
    int m0 = (blockIdx.x - 512) * 16;
    short8 ah = *(const short8*)(feat_h + (size_t)(m0+mr)*32 + q*8);
    short8 al = *(const short8*)(feat_l + (size_t)(m0+mr)*32 + q*8);
    f32x4 acc = {0.f,0.f,0.f,0.f};
    const unsigned short* W1h = Wh + OFF_CONV1;
    const unsigned short* W1l = Wl + OFF_CONV1;
    {
      int wr = (w*16 + mr)*32 + q*8;
      mfma3(acc, ah, al, *(const short8*)(W1h + wr), *(const short8*)(W1l + wr));
    }
    {
      int n = w*16 + mr;
      float b = conv1_b[n];
#pragma unroll
      for (int r = 0; r < 4; ++r) {
        int row = q*4 + r;
        float v = lrelu(acc[r] + b);
        unsigned short hh, ll; split2(v, hh, ll);
        sh_h[row*72 + n] = hh; sh_l[row*72 + n] = ll;
      }
    }
    __syncthreads();
    f32x4 acc2[2];
#pragma unroll
    for (int t = 0; t < 2; ++t) { f32x4 z = {0.f,0.f,0.f,0.f}; acc2[t] = z; }
    const unsigned short* W2h = Wh + OFF_CONV2;
    const unsigned short* W2l = Wl + OFF_CONV2;
#pragma unroll
    for (int ks = 0; ks < 2; ++ks) {
      short8 a2 = *(const short8*)&sh_h[mr*72 + q*8 + ks*32];
      short8 a2l = *(const short8*)&sh_l[mr*72 + q*8 + ks*32];
#pragma unroll
      for (int tt = 0; tt < 2; ++tt) {
        int wr = ((2*w+tt)*16 + mr)*64 + q*8 + ks*32;
        mfma3(acc2[tt], a2, a2l, *(const short8*)(W2h + wr), *(const short8*)(W2l + wr));
      }
    }
#pragma unroll
    for (int tt = 0; tt < 2; ++tt) {
      int n = (2*w+tt)*16 + mr;
      float b = conv2_b[n];
#pragma unroll
      for (int r = 0; r < 4; ++r)
        Yf[(size_t)(m0 + q*4 + r)*128 + n] = acc2[tt][r] + b;
    }
  }
}

// ---------------- pool: float4 gathers, 4-way k-split, LDS partial max --------
__global__ __launch_bounds__(256) void k_pool(const float* __restrict__ Yf,
                                              const float* __restrict__ Yfp,
                                              const float* __restrict__ feat,
                                              const float* __restrict__ pf,
                                              const int* __restrict__ idx,
                                              const float* __restrict__ w,
                                              unsigned short* __restrict__ finh,
                                              unsigned short* __restrict__ finl) {
  int n = blockIdx.x;
  int tid = threadIdx.x;
  __shared__ int sj[32];
  __shared__ float sw[32];
  __shared__ float part[2][4][128];
  if (tid < 32) { sj[tid] = idx[n*32+tid]; sw[tid] = w[n*32+tid]; }
  __syncthreads();
  int arr = tid >> 7;        // 0: Yfp (fp slot), 1: Yf (f slot)
  int kq  = (tid >> 5) & 3;  // k quarter
  int cg  = tid & 31;        // channel group of 4
  const float* Y = arr ? Yf : Yfp;
  float4 acc = {-INFINITY, -INFINITY, -INFINITY, -INFINITY};
#pragma unroll
  for (int kk = 0; kk < 8; ++kk) {
    int k = kq*8 + kk;
    float4 v = *(const float4*)&Y[(size_t)sj[k]*128 + cg*4];
    float wk = sw[k];
    acc.x = fmaxf(acc.x, wk*v.x); acc.y = fmaxf(acc.y, wk*v.y);
    acc.z = fmaxf(acc.z, wk*v.z); acc.w = fmaxf(acc.w, wk*v.w);
  }
  *(float4*)&part[arr][kq][cg*4] = acc;
  __syncthreads();
#define WRS(pos, val) { float v_ = (val); unsigned short h_, l_; split2(v_, h_, l_); \
    finh[(size_t)n*416 + (pos)] = h_; finl[(size_t)n*416 + (pos)] = l_; }
  if (tid < 64) {
    int a2 = tid >> 5, c2 = tid & 31;
    float4 m0v = *(const float4*)&part[a2][0][c2*4];
    float4 m1v = *(const float4*)&part[a2][1][c2*4];
    float4 m2v = *(const float4*)&part[a2][2][c2*4];
    float4 m3v = *(const float4*)&part[a2][3][c2*4];
    int base = a2 ? 160 : 0;   // f at [160,288), fp at [0,128)
    WRS(base + c2*4 + 0, lrelu(fmaxf(fmaxf(m0v.x, m1v.x), fmaxf(m2v.x, m3v.x))));
    WRS(base + c2*4 + 1, lrelu(fmaxf(fmaxf(m0v.y, m1v.y), fmaxf(m2v.y, m3v.y))));
    WRS(base + c2*4 + 2, lrelu(fmaxf(fmaxf(m0v.z, m1v.z), fmaxf(m2v.z, m3v.z))));
    WRS(base + c2*4 + 3, lrelu(fmaxf(fmaxf(m0v.w, m1v.w), fmaxf(m2v.w, m3v.w))));
  } else if (tid < 192) {
    int c = tid - 64;
    WRS(288 + c, lrelu(pf[n*128 + c]));       // pf [288,416)
  } else if (tid < 224) {
    int c = tid - 192;
    WRS(128 + c, lrelu(feat[n*32 + c]));      // feat [128,160)
  }
}

// ---------------- final GEMM (K=416,N=128) + fused g-reduction + kp MLP -------
__global__ __launch_bounds__(256) void k_final_g(const unsigned short* __restrict__ Ah,
                                                 const unsigned short* __restrict__ Al,
                                                 const unsigned short* __restrict__ Wh,
                                                 const unsigned short* __restrict__ Wl,
                                                 const float* __restrict__ bias,
                                                 unsigned short* __restrict__ Ch,
                                                 unsigned short* __restrict__ Cl,
                                                 const float* __restrict__ dc,
                                                 const float* __restrict__ seg,
                                                 float* __restrict__ g,
                                                 const float* __restrict__ l1w, const float* __restrict__ l1b,
                                                 const float* __restrict__ l2w, const float* __restrict__ l2b,
                                                 const float* __restrict__ l3w, const float* __restrict__ l3b,
                                                 float* __restrict__ o_kp) {
  __shared__ float dcseg[16];
  __shared__ int slast;
  int tid = threadIdx.x, lane = tid & 63, w = tid >> 6;
  int mr = lane & 15, q = lane >> 4;
  int m0 = blockIdx.x * 16;
  if (tid < 16) dcseg[tid] = dc[m0 + tid] * seg[m0 + tid];
  f32x4 acc[2];
#pragma unroll
  for (int t = 0; t < 2; ++t) { f32x4 z = {0.f,0.f,0.f,0.f}; acc[t] = z; }
  const unsigned short* arh = Ah + (size_t)(m0 + mr) * 416 + q * 8;
  const unsigned short* arl = Al + (size_t)(m0 + mr) * 416 + q * 8;
#pragma unroll
  for (int ks = 0; ks < 13; ++ks) {
    short8 ah = *(const short8*)(arh + ks * 32);
    short8 al = *(const short8*)(arl + ks * 32);
#pragma unroll
    for (int tt = 0; tt < 2; ++tt) {
      int wr = ((2*w+tt)*16 + mr)*416 + q*8 + ks*32;
      mfma3(acc[tt], ah, al, *(const short8*)(Wh + wr), *(const short8*)(Wl + wr));
    }
  }
  __syncthreads();   // dcseg visible
#pragma unroll
  for (int tt = 0; tt < 2; ++tt) {
    int n = (2*w+tt)*16 + mr;
    float b = bias[n];
    float s = 0.f;
#pragma unroll
    for (int r = 0; r < 4; ++r) {
      int row = m0 + q*4 + r;
      float v = acc[tt][r] + b;
      s += v * dcseg[q*4 + r];
      unsigned short hh, ll; split2(v, hh, ll);
      Ch[(size_t)row*128 + n] = hh;
      Cl[(size_t)row*128 + n] = ll;
    }
    s += __shfl_xor(s, 16, 64);
    s += __shfl_xor(s, 32, 64);
    if (q == 0) atomicAdd(&g[n], s);
  }
  __threadfence();
  __syncthreads();
  if (tid == 0) slast = (atomicAdd((int*)(g + 128), 1) == 511);
  __syncthreads();
  if (!slast) return;
  // last block: keypoint MLP 128->90->64->24
  __shared__ float sg[128], s1[90], s2[64];
  if (tid < 128) sg[tid] = atomicAdd(&g[tid], 0.f);
  __syncthreads();
  if (tid < 90) {
    float a = l1b[tid];
    for (int i = 0; i < 128; ++i) a += sg[i]*l1w[tid*128+i];
    s1[tid] = lrelu(a);
  }
  __syncthreads();
  if (tid < 64) {
    float a = l2b[tid];
    for (int i = 0; i < 90; ++i) a += s1[i]*l2w[tid*90+i];
    s2[tid] = lrelu(a);
  }
  __syncthreads();
  if (tid < 24) {
    float a = l3b[tid];
    for (int i = 0; i < 64; ++i) a += s2[i]*l3w[tid*64+i];
    o_kp[tid] = a;
  }
}

// ---------------- conv3 + head fused: 4 waves/m-tile, t-split -----------------
__global__ __launch_bounds__(256) void k_c3head(const unsigned short* __restrict__ Ah,
                                               const unsigned short* __restrict__ Al,
                                               const unsigned short* __restrict__ Wh,
                                               const unsigned short* __restrict__ Wl,
                                               const float* __restrict__ biasc,
                                               const float* __restrict__ bias2c,
                                               const float* __restrict__ segw, const float* __restrict__ segb,
                                               const float* __restrict__ disw, const float* __restrict__ disb,
                                               float* __restrict__ osegp, float* __restrict__ odisp) {
  __shared__ unsigned short t1h[2176], t1l[2176];
  __shared__ float shead[4][16][17];
  int tid = threadIdx.x, lane = tid & 63, w = tid >> 6;
  int mr = lane & 15, q = lane >> 4;
  int m0 = blockIdx.x * 16;
  f32x4 acc[2];
#pragma unroll
  for (int t = 0; t < 2; ++t) { f32x4 z = {0.f,0.f,0.f,0.f}; acc[t] = z; }
  const unsigned short* W3h = Wh + OFF_W3;
  const unsigned short* W3l = Wl + OFF_W3;
#pragma unroll
  for (int ks = 0; ks < 12; ++ks) {
    int tap = ks >> 2;
    int kin = (ks & 3)*32 + q*8;
    int ar = m0 + mr + tap - 1;
    short8 ah = {0,0,0,0,0,0,0,0}, al = {0,0,0,0,0,0,0,0};
    if (ar >= 0 && ar < NPT) {
      ah = *(const short8*)(Ah + (size_t)ar*128 + kin);
      al = *(const short8*)(Al + (size_t)ar*128 + kin);
    }
#pragma unroll
    for (int tt = 0; tt < 2; ++tt) {
      int wr = ((2*w+tt)*16 + mr)*384 + ks*32 + q*8;
      mfma3(acc[tt], ah, al, *(const short8*)(W3h + wr), *(const short8*)(W3l + wr));
    }
  }
#pragma unroll
  for (int tt = 0; tt < 2; ++tt) {
    int n = (2*w+tt)*16 + mr;
    float b = biasc[n];
#pragma unroll
    for (int r = 0; r < 4; ++r) {
      int row = q*4 + r;
      float v = lrelu(acc[tt][r] + b);
      unsigned short hh, ll; split2(v, hh, ll);
      t1h[row*136 + n] = hh; t1l[row*136 + n] = ll;
    }
  }
  __syncthreads();
  f32x4 acc2 = {0.f,0.f,0.f,0.f};
  const unsigned short* WPh = Wh + OFF_W2P;
  const unsigned short* WPl = Wl + OFF_W2P;
#pragma unroll
  for (int ks = 0; ks < 4; ++ks) {
    short8 ah = *(const short8*)&t1h[mr*136 + q*8 + ks*32];
    short8 al = *(const short8*)&t1l[mr*136 + q*8 + ks*32];
    int wr = (w*16 + mr)*128 + q*8 + ks*32;
    mfma3(acc2, ah, al, *(const short8*)(WPh + wr), *(const short8*)(WPl + wr));
  }
  float hw = (w < 2) ? segw[w*16 + mr] : disw[(w-2)*16 + mr];
  float bb = bias2c[w*16 + mr];
#pragma unroll
  for (int r = 0; r < 4; ++r)
    shead[w][q*4 + r][mr] = lrelu(acc2[r] + bb) * hw;
  __syncthreads();
  if (tid < 16) {
    float a = 0.f;
#pragma unroll
    for (int i = 0; i < 16; ++i) a += shead[0][tid][i] + shead[1][tid][i];
    osegp[m0 + tid] = a + segb[0];
  } else if (tid < 32) {
    float a = 0.f;
#pragma unroll
    for (int i = 0; i < 16; ++i) a += shead[2][tid-16][i] + shead[3][tid-16][i];
    odisp[m0 + tid - 16] = a + disb[0];
  }
}

extern "C" void kernel_launch(void* const* d_in, const int* in_sizes, int n_in,
                              void* d_out, int out_size, void* d_ws, size_t ws_size,
                              hipStream_t stream) {
  const float* seg      = (const float*)d_in[0];
  const float* img      = (const float*)d_in[1];
  const float* cloud    = (const float*)d_in[2];
  const float* tvec     = (const float*)d_in[3];
  const int*   choose   = (const int*)d_in[4];
  const float* pconv1_w = (const float*)d_in[5];
  const float* pconv1_b = (const float*)d_in[6];
  const float* pconv2_w = (const float*)d_in[7];
  const float* pconv2_b = (const float*)d_in[8];
  const float* conv1_w  = (const float*)d_in[9];
  const float* conv1_b  = (const float*)d_in[10];
  const float* conv2_w  = (const float*)d_in[11];
  const float* conv2_b  = (const float*)d_in[12];
  const float* psconv1_w= (const float*)d_in[13];
  const float* psconv1_b= (const float*)d_in[14];
  const float* psconv2_w= (const float*)d_in[15];
  const float* psconv2_b= (const float*)d_in[16];
  const float* final_w  = (const float*)d_in[17];
  const float* final_b  = (const float*)d_in[18];
  const float* seg1_w   = (const float*)d_in[19];
  const float* seg1_b   = (const float*)d_in[20];
  const float* seg2_w   = (const float*)d_in[21];
  const float* seg2_b   = (const float*)d_in[22];
  const float* seg3_w   = (const float*)d_in[23];
  const float* seg3_b   = (const float*)d_in[24];
  const float* dis1_w   = (const float*)d_in[25];
  const float* dis1_b   = (const float*)d_in[26];
  const float* dis2_w   = (const float*)d_in[27];
  const float* dis2_b   = (const float*)d_in[28];
  const float* dis3_w   = (const float*)d_in[29];
  const float* dis3_b   = (const float*)d_in[30];
  const float* lin1_w   = (const float*)d_in[31];
  const float* lin1_b   = (const float*)d_in[32];
  const float* lin2_w   = (const float*)d_in[33];
  const float* lin2_b   = (const float*)d_in[34];
  const float* lin3_w   = (const float*)d_in[35];
  const float* lin3_b   = (const float*)d_in[36];

  float* out = (float*)d_out;
  float* ws  = (float*)d_ws;

  // workspace layout (float offsets)
  float* c4     = ws + 0;          // 32768
  float* feat   = ws + 32768;      // 262144
  unsigned short* feat_h = (unsigned short*)(ws + 294912);   // 131072 f
  unsigned short* feat_l = (unsigned short*)(ws + 425984);   // 131072 f
  float* pf     = ws + 557056;     // 1048576
  float* Yf     = ws + 1605632;    // 1048576
  float* Yfp    = ws + 2654208;    // 1048576
  int*   idx    = (int*)(ws + 3702784);   // 262144
  float* wsm    = ws + 3964928;    // 262144
  unsigned short* finh  = (unsigned short*)(ws + 4227072);   // 1703936 f
  unsigned short* finl  = (unsigned short*)(ws + 5931008);   // 1703936 f
  unsigned short* fusedh = (unsigned short*)(ws + 8683520);  // 524288 f
  unsigned short* fusedl = (unsigned short*)(ws + 9207808);  // 524288 f
  unsigned short* Wh    = (unsigned short*)(ws + 9732096);   // 97280 f
  unsigned short* Wl    = (unsigned short*)(ws + 9829376);   // 97280 f
  float* biasc  = ws + 9926656;    // 128
  float* bias2c = ws + 9926784;    // 64
  float* g      = ws + 9926848;    // 129 (g[128] = block counter)

  float* o_kp   = out;             // 24
  float* o_disp = out + 24;        // 8192
  float* o_dc   = out + 8216;      // 8192
  float* o_segp = out + 16408;     // 8192

  k_prep0<<<(NPT + 129 + 255)/256, 256, 0, stream>>>(cloud, c4, g);

  k_mega<<<MEGA_GRID, 256, 0, stream>>>(
      (const float4*)c4, idx, wsm, cloud, tvec, o_dc,
      choose, img, seg1_w, dis1_w, seg1_b, dis1_b,
      seg2_w, dis2_w, seg2_b, dis2_b,
      pconv2_w, conv1_w, conv2_w, psconv1_w, psconv2_w, final_w,
      biasc, bias2c, feat, feat_h, feat_l, Wh, Wl);

  k_chain<<<1024, 256, 0, stream>>>(
      (const float4*)c4, pconv1_w, pconv1_b, pconv2_b, psconv1_b, psconv2_b,
      feat_h, feat_l, conv1_b, conv2_b, Wh, Wl, pf, Yfp, Yf);

  k_pool<<<NPT, 256, 0, stream>>>(Yf, Yfp, feat, pf, idx, wsm, finh, finl);

  k_final_g<<<512, 256, 0, stream>>>(finh, finl, Wh + OFF_FINAL, Wl + OFF_FINAL,
                                     final_b, fusedh, fusedl,
                                     o_dc, seg, g,
                                     lin1_w, lin1_b, lin2_w, lin2_b, lin3_w, lin3_b, o_kp);

  k_c3head<<<512, 256, 0, stream>>>(fusedh, fusedl, Wh, Wl, biasc, bias2c,
                                    seg3_w, seg3_b, dis3_w, dis3_b, o_segp, o_disp);

  (void)in_sizes; (void)n_in; (void)out_size; (void)ws_size;
}

// Round 8
// 244.136 us; speedup vs baseline: 1.3249x; 1.3249x over previous
//
#include <hip/hip_runtime.h>
#include <math.h>

#define NPT 8192
#define HWIMG 19200
#define KCAP 128

using short8 = __attribute__((ext_vector_type(8))) short;
using f32x4  = __attribute__((ext_vector_type(4))) float;

__device__ __forceinline__ float lrelu(float x) { return x > 0.f ? x : 0.01f * x; }
__device__ __forceinline__ unsigned short f2bf(float v) {
  unsigned u = __float_as_uint(v);
  return (unsigned short)((u + 0x7fffu + ((u >> 16) & 1u)) >> 16);
}
__device__ __forceinline__ float bf2f(unsigned short h) {
  return __uint_as_float(((unsigned)h) << 16);
}
__device__ __forceinline__ void split2(float v, unsigned short& h, unsigned short& l) {
  h = f2bf(v);
  l = f2bf(v - bf2f(h));
}
__device__ __forceinline__ void mfma3(f32x4& acc, short8 ah, short8 al, short8 wh, short8 wl) {
  acc = __builtin_amdgcn_mfma_f32_16x16x32_bf16(ah, wh, acc, 0, 0, 0);
  acc = __builtin_amdgcn_mfma_f32_16x16x32_bf16(al, wh, acc, 0, 0, 0);
  acc = __builtin_amdgcn_mfma_f32_16x16x32_bf16(ah, wl, acc, 0, 0, 0);
}

// fragment-sequential swizzle: element (row o, k) of a [N,K] matrix lives at
// chunk ((o/16)*Kc + k/32)*64 + (k/8)%4*16 + o%16, byte-offset k%8 within the
// 8-short chunk. A wave's (tile,ks) fragment load = base + lane*16B (coalesced).
__device__ __forceinline__ int swz(int o, int k, int Kc) {
  return ((((o >> 4) * Kc + (k >> 5)) << 6) + (((k >> 3) & 3) << 4) + (o & 15)) * 8 + (k & 7);
}

// weight-plane segment offsets (in shorts)
#define OFF_PCONV2  0
#define OFF_CONV1   8192
#define OFF_CONV2   10240
#define OFF_PSCONV1 18432
#define OFF_PSCONV2 51200
#define OFF_FINAL   83968
#define OFF_W3      137216
#define OFF_W2P     186368

#define PR_W3    49152
#define PR_BIASC 128
#define PR_W2P   8192
#define PR_B2C   64
#define PR_FEAT  (NPT*32)
#define PR_WSPL  OFF_W3
#define PREP_REST (PR_W3 + PR_BIASC + PR_W2P + PR_B2C + PR_FEAT + PR_WSPL)
#define MEGA_GRID (2049 + (PREP_REST + 255)/256)

// ---------------- prep0: c4 pack + g/counter zero ------------------------------
__global__ void k_prep0(const float* __restrict__ cloud, float* __restrict__ c4,
                        float* __restrict__ g) {
  int i = blockIdx.x * blockDim.x + threadIdx.x;
  if (i < NPT) {
    float x = cloud[i*3+0], y = cloud[i*3+1], z = cloud[i*3+2];
    float4 v; v.x = x; v.y = y; v.z = z; v.w = x*x + y*y + z*z;
    ((float4*)c4)[i] = v;
  }
  int j = i - NPT;
  if (j >= 0 && j < 129) g[j] = 0.f;
}

// ---------------- bitonic helpers ---------------------------------------------
__device__ __forceinline__ unsigned long long bsort64(unsigned long long key, int lane) {
#pragma unroll
  for (int k = 2; k <= 64; k <<= 1) {
#pragma unroll
    for (int j = k >> 1; j > 0; j >>= 1) {
      unsigned long long o = __shfl_xor(key, j, 64);
      bool keepmin = (((lane & j) == 0) == ((lane & k) == 0));
      bool omin = o < key;
      key = (omin == keepmin) ? o : key;
    }
  }
  return key;
}
__device__ __forceinline__ unsigned long long bmerge64(unsigned long long key, int lane) {
#pragma unroll
  for (int j = 32; j > 0; j >>= 1) {
    unsigned long long o = __shfl_xor(key, j, 64);
    bool keepmin = ((lane & j) == 0);
    bool omin = o < key;
    key = (omin == keepmin) ? o : key;
  }
  return key;
}

// ---------------- mega: knn (0..2047) | dis_center (2048) | prep-rest ----------
__global__ __launch_bounds__(256) void k_mega(const float4* __restrict__ c4,
                                              int* __restrict__ idxo, float* __restrict__ wo,
                                              const float* __restrict__ cloud,
                                              const float* __restrict__ tvec,
                                              float* __restrict__ dc,
                                              const int* __restrict__ choose,
                                              const float* __restrict__ img,
                                              const float* __restrict__ seg1_w, const float* __restrict__ dis1_w,
                                              const float* __restrict__ seg1_b, const float* __restrict__ dis1_b,
                                              const float* __restrict__ seg2_w, const float* __restrict__ dis2_w,
                                              const float* __restrict__ seg2_b, const float* __restrict__ dis2_b,
                                              const float* __restrict__ pconv2_w, const float* __restrict__ conv1_w,
                                              const float* __restrict__ conv2_w, const float* __restrict__ psconv1_w,
                                              const float* __restrict__ psconv2_w, const float* __restrict__ final_w,
                                              float* __restrict__ biasc, float* __restrict__ bias2c,
                                              float* __restrict__ feat,
                                              unsigned short* __restrict__ feat_h,
                                              unsigned short* __restrict__ feat_l,
                                              unsigned short* __restrict__ Wh,
                                              unsigned short* __restrict__ Wl) {
  int tid = threadIdx.x, lane = tid & 63, wv = tid >> 6;
  if (blockIdx.x > 2048) {
    int j = (blockIdx.x - 2049) * 256 + tid;
    if (j < PR_W3) {                       // conv3 weight transpose + split (swizzled)
      int h = j / 24576, r = j - h*24576, o = r / 384, k = r - o*384;
      int t = k >> 7, c = k & 127;
      float v = (h ? dis1_w : seg1_w)[o*384 + c*3 + t];
      unsigned short hh, ll; split2(v, hh, ll);
      int d = OFF_W3 + swz(h*64 + o, k, 12);
      Wh[d] = hh; Wl[d] = ll;
      return;
    }
    j -= PR_W3;
    if (j < PR_BIASC) { biasc[j] = (j < 64) ? seg1_b[j] : dis1_b[j-64]; return; }
    j -= PR_BIASC;
    if (j < PR_W2P) {                      // W2p block-diag + split (swizzled)
      int o = j >> 7, c = j & 127;
      float v = 0.f;
      if (o < 32) { if (c < 64) v = seg2_w[o*64 + c]; }
      else        { if (c >= 64) v = dis2_w[(o-32)*64 + (c-64)]; }
      unsigned short hh, ll; split2(v, hh, ll);
      int d = OFF_W2P + swz(o, c, 4);
      Wh[d] = hh; Wl[d] = ll;
      return;
    }
    j -= PR_W2P;
    if (j < PR_B2C) { bias2c[j] = (j < 32) ? seg2_b[j] : dis2_b[j-32]; return; }
    j -= PR_B2C;
    if (j < PR_FEAT) {                     // feat gather + split (swizzled planes)
      int n = j >> 5, ch = j & 31;
      float v = img[ch*HWIMG + choose[n]];
      feat[j] = v;
      unsigned short hh, ll; split2(v, hh, ll);
      int d = swz(n, ch, 1);
      feat_h[d] = hh; feat_l[d] = ll;
      return;
    }
    j -= PR_FEAT;
    if (j < PR_WSPL) {                     // weight split (swizzled)
      float v; int d;
      if (j < OFF_CONV1) {                               // pconv2 [128,64]
        int o = j >> 6, k = j & 63;
        v = pconv2_w[j]; d = OFF_PCONV2 + swz(o, k, 2);
      } else if (j < OFF_CONV2) {                        // conv1 [64,32]
        int jj = j - OFF_CONV1, o = jj >> 5, k = jj & 31;
        v = conv1_w[jj]; d = OFF_CONV1 + swz(o, k, 1);
      } else if (j < OFF_PSCONV1) {                      // conv2 [128,64]
        int jj = j - OFF_CONV2, o = jj >> 6, k = jj & 63;
        v = conv2_w[jj]; d = OFF_CONV2 + swz(o, k, 2);
      } else if (j < OFF_PSCONV2) {                      // psconv1 [256,128]
        int jj = j - OFF_PSCONV1, o = jj >> 7, k = jj & 127;
        v = psconv1_w[jj]; d = OFF_PSCONV1 + swz(o, k, 4);
      } else if (j < OFF_FINAL) {                        // psconv2 [128,256]
        int jj = j - OFF_PSCONV2, o = jj >> 8, k = jj & 255;
        v = psconv2_w[jj]; d = OFF_PSCONV2 + swz(o, k, 8);
      } else {                                           // final [128,416]
        int jj = j - OFF_FINAL, o = jj / 416, k = jj - o*416;
        v = final_w[jj]; d = OFF_FINAL + swz(o, k, 13);
      }
      unsigned short hh, ll; split2(v, hh, ll);
      Wh[d] = hh; Wl[d] = ll;
    }
    return;
  }
  if (blockIdx.x == 2048) {
    __shared__ float sred[4];
    float tx = tvec[0], ty = tvec[1], tz = tvec[2];
    float v[32];
    float m = -INFINITY;
#pragma unroll
    for (int i2 = 0; i2 < 32; ++i2) {
      int n = i2*256 + tid;
      float ax = cloud[n*3+0] + tx, ay = cloud[n*3+1] + ty, az = cloud[n*3+2] + tz;
      v[i2] = sqrtf(ax*ax + ay*ay + az*az);
      m = fmaxf(m, v[i2]);
    }
#pragma unroll
    for (int o = 1; o < 64; o <<= 1) m = fmaxf(m, __shfl_xor(m, o, 64));
    if (lane == 0) sred[wv] = m;
    __syncthreads();
    m = fmaxf(fmaxf(sred[0], sred[1]), fmaxf(sred[2], sred[3]));
    __syncthreads();
    float s = 0.f;
#pragma unroll
    for (int i2 = 0; i2 < 32; ++i2) { v[i2] = expf(v[i2] - m); s += v[i2]; }
#pragma unroll
    for (int o = 1; o < 64; o <<= 1) s += __shfl_xor(s, o, 64);
    if (lane == 0) sred[wv] = s;
    __syncthreads();
    s = sred[0] + sred[1] + sred[2] + sred[3];
#pragma unroll
    for (int i2 = 0; i2 < 32; ++i2) dc[i2*256 + tid] = v[i2] / s;
    return;
  }
  // ---- knn ----
  __shared__ float smin[4][256];
  __shared__ float sT[4];
  __shared__ float sd[4][KCAP];
  __shared__ int   sj[4][KCAP];
  __shared__ int   scnt[4];
  int q0 = blockIdx.x * 4;
  float4 p0 = c4[q0], p1 = c4[q0+1], p2 = c4[q0+2], p3 = c4[q0+3];
  float p0x = -2.f*p0.x, p0y = -2.f*p0.y, p0z = -2.f*p0.z;
  float p1x = -2.f*p1.x, p1y = -2.f*p1.y, p1z = -2.f*p1.z;
  float p2x = -2.f*p2.x, p2y = -2.f*p2.y, p2z = -2.f*p2.z;
  float p3x = -2.f*p3.x, p3y = -2.f*p3.y, p3z = -2.f*p3.z;
#define DDOT(PX,PY,PZ,PW,CJ) fmaf(PX,(CJ).x, fmaf(PY,(CJ).y, fmaf(PZ,(CJ).z, PW + (CJ).w)))
  float m0 = INFINITY, m1 = INFINITY, m2 = INFINITY, m3 = INFINITY;
  for (int t = 0; t < 32; ++t) {
    float4 cj = c4[t*256 + tid];
    m0 = fminf(m0, DDOT(p0x,p0y,p0z,p0.w,cj));
    m1 = fminf(m1, DDOT(p1x,p1y,p1z,p1.w,cj));
    m2 = fminf(m2, DDOT(p2x,p2y,p2z,p2.w,cj));
    m3 = fminf(m3, DDOT(p3x,p3y,p3z,p3.w,cj));
  }
  smin[0][tid] = m0; smin[1][tid] = m1; smin[2][tid] = m2; smin[3][tid] = m3;
  if (tid < 4) scnt[tid] = 0;
  __syncthreads();
  {
    float4 vv = *(const float4*)&smin[wv][lane*4];
    float v0 = vv.x, v1 = vv.y, v2 = vv.z, v3 = vv.w;
#define CSV(a,b) { if (b < a) { float t_ = a; a = b; b = t_; } }
    CSV(v0,v2) CSV(v1,v3) CSV(v0,v1) CSV(v2,v3) CSV(v1,v2)
    float T = 0.f;
    for (int it = 0; it < 32; ++it) {
      float mn = v0;
#pragma unroll
      for (int o = 1; o < 64; o <<= 1) mn = fminf(mn, __shfl_xor(mn, o, 64));
      T = mn;
      if (v0 == mn) { v0 = v1; v1 = v2; v2 = v3; v3 = INFINITY; }
    }
    if (lane == 0) sT[wv] = T * (1.f + 2e-5f) + 4e-5f;
  }
  __syncthreads();
  float T0 = sT[0], T1 = sT[1], T2 = sT[2], T3 = sT[3];
  for (int t = 0; t < 32; ++t) {
    int j = t*256 + tid;
    float4 cj = c4[j];
    float d;
#define APPEND(Q, P) { \
    float dx_ = (P).x-cj.x, dy_ = (P).y-cj.y, dz_ = (P).z-cj.z; \
    float de_ = dx_*dx_ + dy_*dy_ + dz_*dz_; \
    int p_ = atomicAdd(&scnt[Q],1); if (p_ < KCAP) { sd[Q][p_] = de_; sj[Q][p_] = j; } }
    d = DDOT(p0x,p0y,p0z,p0.w,cj); if (d <= T0) APPEND(0, p0);
    d = DDOT(p1x,p1y,p1z,p1.w,cj); if (d <= T1) APPEND(1, p1);
    d = DDOT(p2x,p2y,p2z,p2.w,cj); if (d <= T2) APPEND(2, p2);
    d = DDOT(p3x,p3y,p3z,p3.w,cj); if (d <= T3) APPEND(3, p3);
  }
  __syncthreads();
  int M = scnt[wv]; if (M > KCAP) M = KCAP;
  unsigned long long key = (lane < M)
      ? (((unsigned long long)__float_as_uint(sd[wv][lane]) << 32) | (unsigned)sj[wv][lane])
      : ~0ull;
  key = bsort64(key, lane);
  for (int base = 64; base < M; base += 64) {
    unsigned long long nk = (base + lane < M)
        ? (((unsigned long long)__float_as_uint(sd[wv][base+lane]) << 32) | (unsigned)sj[wv][base+lane])
        : ~0ull;
    nk = bsort64(nk, lane);
    nk = __shfl_xor(nk, 63, 64);
    key = key < nk ? key : nk;
    key = bmerge64(key, lane);
  }
  float dsel = __uint_as_float((unsigned)(key >> 32));
  int   jsel = (int)(unsigned)(key & 0xffffffffu);
  float v = -sqrtf(dsel);
  float mx = v;
#pragma unroll
  for (int o = 1; o < 32; o <<= 1) mx = fmaxf(mx, __shfl_xor(mx, o, 64));
  float e = expf(v - mx);
  float s = e;
#pragma unroll
  for (int o = 1; o < 32; o <<= 1) s += __shfl_xor(s, o, 64);
  if (lane < 32) {
    int q = q0 + wv;
    wo[q*32 + lane] = e / s;
    idxo[q*32 + lane] = jsel;
  }
}

// ---------------- fused MLP chains (all loads coalesced via swizzle) -----------
__global__ __launch_bounds__(256) void k_chain(const float4* __restrict__ c4,
                                              const float* __restrict__ pconv1_w, const float* __restrict__ pconv1_b,
                                              const float* __restrict__ pconv2_b, const float* __restrict__ psconv1_b,
                                              const float* __restrict__ psconv2_b,
                                              const unsigned short* __restrict__ feat_h,
                                              const unsigned short* __restrict__ feat_l,
                                              const float* __restrict__ conv1_b, const float* __restrict__ conv2_b,
                                              const unsigned short* __restrict__ Wh,
                                              const unsigned short* __restrict__ Wl,
                                              float* __restrict__ pf, float* __restrict__ Yfp,
                                              float* __restrict__ Yf) {
  // LDS: chunk-order regions. point: A(K=128,Kc=4)=2048 sh @0, B(K=256,Kc=8)=4096 sh @2048
  __shared__ unsigned short sh_h[6144], sh_l[6144];
  int tid = threadIdx.x, lane = tid & 63, w = tid >> 6;
  int mr = lane & 15, q = lane >> 4;
  if (blockIdx.x < 512) {
    int m0 = blockIdx.x * 16;
    // stage 1: pconv1 (K=3) directly in A-frag ownership (frag = chunks ks0,ks1)
    float4 cp = c4[m0 + mr];
    short8 ah0, al0, ah1, al1;
#pragma unroll
    for (int j = 0; j < 8; ++j) {
      int c0 = q*8 + j, c1 = 32 + q*8 + j;
      float v0 = lrelu(fmaf(cp.x, pconv1_w[c0*3+0], fmaf(cp.y, pconv1_w[c0*3+1],
                        fmaf(cp.z, pconv1_w[c0*3+2], pconv1_b[c0]))));
      float v1 = lrelu(fmaf(cp.x, pconv1_w[c1*3+0], fmaf(cp.y, pconv1_w[c1*3+1],
                        fmaf(cp.z, pconv1_w[c1*3+2], pconv1_b[c1]))));
      unsigned short hh, ll;
      split2(v0, hh, ll); ah0[j] = (short)hh; al0[j] = (short)ll;
      split2(v1, hh, ll); ah1[j] = (short)hh; al1[j] = (short)ll;
    }
    // stage 2: pconv2 (K=64, Kc=2, N=128), wave w -> t {2w,2w+1}
    f32x4 acc[2];
#pragma unroll
    for (int t = 0; t < 2; ++t) { f32x4 z = {0.f,0.f,0.f,0.f}; acc[t] = z; }
    const unsigned short* W2h = Wh + OFF_PCONV2;
    const unsigned short* W2l = Wl + OFF_PCONV2;
#pragma unroll
    for (int tt = 0; tt < 2; ++tt) {
      int t1 = 2*w + tt;
      int w0 = ((t1*2 + 0)*64 + lane)*8, w1 = ((t1*2 + 1)*64 + lane)*8;
      mfma3(acc[tt], ah0, al0, *(const short8*)(W2h + w0), *(const short8*)(W2l + w0));
      mfma3(acc[tt], ah1, al1, *(const short8*)(W2h + w1), *(const short8*)(W2l + w1));
    }
#pragma unroll
    for (int tt = 0; tt < 2; ++tt) {
      int t1 = 2*w + tt, n = t1*16 + mr;
      float b = pconv2_b[n];
      int ks2 = t1 >> 1, q2 = (t1 & 1)*2 + (mr >> 3), jd = mr & 7;
#pragma unroll
      for (int r = 0; r < 4; ++r) {
        int row = q*4 + r;
        float v = acc[tt][r] + b;
        pf[(size_t)(m0+row)*128 + n] = v;
        unsigned short hh, ll; split2(v, hh, ll);
        int p = ((ks2*16 + row)*4 + q2)*8 + jd;
        sh_h[p] = hh; sh_l[p] = ll;
      }
    }
    __syncthreads();
    // stage 3: psconv1 (K=128, Kc=4, N=256), wave w -> t {4w..4w+3}
    f32x4 acc2[4];
#pragma unroll
    for (int t = 0; t < 4; ++t) { f32x4 z = {0.f,0.f,0.f,0.f}; acc2[t] = z; }
    const unsigned short* W3h = Wh + OFF_PSCONV1;
    const unsigned short* W3l = Wl + OFF_PSCONV1;
#pragma unroll
    for (int ks = 0; ks < 4; ++ks) {
      int ap = ((ks*16 + mr)*4 + q)*8;
      short8 ah = *(const short8*)&sh_h[ap];
      short8 al = *(const short8*)&sh_l[ap];
#pragma unroll
      for (int tt = 0; tt < 4; ++tt) {
        int wb = (((4*w+tt)*4 + ks)*64 + lane)*8;
        mfma3(acc2[tt], ah, al, *(const short8*)(W3h + wb), *(const short8*)(W3l + wb));
      }
    }
    __syncthreads();
#pragma unroll
    for (int tt = 0; tt < 4; ++tt) {
      int t2 = 4*w + tt, n = t2*16 + mr;
      float b = psconv1_b[n];
      int ks3 = t2 >> 1, q3 = (t2 & 1)*2 + (mr >> 3), jd = mr & 7;
#pragma unroll
      for (int r = 0; r < 4; ++r) {
        int row = q*4 + r;
        float v = lrelu(acc2[tt][r] + b);
        unsigned short hh, ll; split2(v, hh, ll);
        int p = 2048 + ((ks3*16 + row)*4 + q3)*8 + jd;
        sh_h[p] = hh; sh_l[p] = ll;
      }
    }
    __syncthreads();
    // stage 4: psconv2 (K=256, Kc=8, N=128) -> Yfp
    f32x4 acc3[2];
#pragma unroll
    for (int t = 0; t < 2; ++t) { f32x4 z = {0.f,0.f,0.f,0.f}; acc3[t] = z; }
    const unsigned short* W4h = Wh + OFF_PSCONV2;
    const unsigned short* W4l = Wl + OFF_PSCONV2;
#pragma unroll
    for (int ks = 0; ks < 8; ++ks) {
      int ap = 2048 + ((ks*16 + mr)*4 + q)*8;
      short8 ah = *(const short8*)&sh_h[ap];
      short8 al = *(const short8*)&sh_l[ap];
#pragma unroll
      for (int tt = 0; tt < 2; ++tt) {
        int wb = (((2*w+tt)*8 + ks)*64 + lane)*8;
        mfma3(acc3[tt], ah, al, *(const short8*)(W4h + wb), *(const short8*)(W4l + wb));
      }
    }
#pragma unroll
    for (int tt = 0; tt < 2; ++tt) {
      int n = (2*w+tt)*16 + mr;
      float b = psconv2_b[n];
#pragma unroll
      for (int r = 0; r < 4; ++r)
        Yfp[(size_t)(m0 + q*4 + r)*128 + n] = acc3[tt][r] + b;
    }
  } else {
    int m0 = (blockIdx.x - 512) * 16;
    // conv1 (K=32, Kc=1, N=64), wave w -> t = w
    int ab = ((m0 >> 4)*64 + lane)*8;
    short8 ah = *(const short8*)(feat_h + ab);
    short8 al = *(const short8*)(feat_l + ab);
    f32x4 acc = {0.f,0.f,0.f,0.f};
    const unsigned short* W1h = Wh + OFF_CONV1;
    const unsigned short* W1l = Wl + OFF_CONV1;
    {
      int wb = (w*64 + lane)*8;
      mfma3(acc, ah, al, *(const short8*)(W1h + wb), *(const short8*)(W1l + wb));
    }
    {
      int n = w*16 + mr;
      float b = conv1_b[n];
      int ks2 = n >> 5, q2 = (n >> 3) & 3, jd = mr & 7;
#pragma unroll
      for (int r = 0; r < 4; ++r) {
        int row = q*4 + r;
        float v = lrelu(acc[r] + b);
        unsigned short hh, ll; split2(v, hh, ll);
        int p = ((ks2*16 + row)*4 + q2)*8 + jd;
        sh_h[p] = hh; sh_l[p] = ll;
      }
    }
    __syncthreads();
    // conv2 (K=64, Kc=2, N=128) -> Yf
    f32x4 acc2[2];
#pragma unroll
    for (int t = 0; t < 2; ++t) { f32x4 z = {0.f,0.f,0.f,0.f}; acc2[t] = z; }
    const unsigned short* W2h = Wh + OFF_CONV2;
    const unsigned short* W2l = Wl + OFF_CONV2;
#pragma unroll
    for (int ks = 0; ks < 2; ++ks) {
      int ap = ((ks*16 + mr)*4 + q)*8;
      short8 a2 = *(const short8*)&sh_h[ap];
      short8 a2l = *(const short8*)&sh_l[ap];
#pragma unroll
      for (int tt = 0; tt < 2; ++tt) {
        int wb = (((2*w+tt)*2 + ks)*64 + lane)*8;
        mfma3(acc2[tt], a2, a2l, *(const short8*)(W2h + wb), *(const short8*)(W2l + wb));
      }
    }
#pragma unroll
    for (int tt = 0; tt < 2; ++tt) {
      int n = (2*w+tt)*16 + mr;
      float b = conv2_b[n];
#pragma unroll
      for (int r = 0; r < 4; ++r)
        Yf[(size_t)(m0 + q*4 + r)*128 + n] = acc2[tt][r] + b;
    }
  }
}

// ---------------- pool: float4 gathers -> sfin LDS -> 16B swizzled chunks ------
__global__ __launch_bounds__(256) void k_pool(const float* __restrict__ Yf,
                                              const float* __restrict__ Yfp,
                                              const float* __restrict__ feat,
                                              const float* __restrict__ pf,
                                              const int* __restrict__ idx,
                                              const float* __restrict__ w,
                                              unsigned short* __restrict__ finh,
                                              unsigned short* __restrict__ finl) {
  int n = blockIdx.x;
  int tid = threadIdx.x;
  __shared__ int sj[32];
  __shared__ float sw[32];
  __shared__ float part[2][4][128];
  __shared__ float sfin[416];
  if (tid < 32) { sj[tid] = idx[n*32+tid]; sw[tid] = w[n*32+tid]; }
  __syncthreads();
  int arr = tid >> 7, kq = (tid >> 5) & 3, cg = tid & 31;
  const float* Y = arr ? Yf : Yfp;
  float4 acc = {-INFINITY, -INFINITY, -INFINITY, -INFINITY};
#pragma unroll
  for (int kk = 0; kk < 8; ++kk) {
    int k = kq*8 + kk;
    float4 v = *(const float4*)&Y[(size_t)sj[k]*128 + cg*4];
    float wk = sw[k];
    acc.x = fmaxf(acc.x, wk*v.x); acc.y = fmaxf(acc.y, wk*v.y);
    acc.z = fmaxf(acc.z, wk*v.z); acc.w = fmaxf(acc.w, wk*v.w);
  }
  *(float4*)&part[arr][kq][cg*4] = acc;
  __syncthreads();
  if (tid < 64) {
    int a2 = tid >> 5, c2 = tid & 31;
    float4 m0v = *(const float4*)&part[a2][0][c2*4];
    float4 m1v = *(const float4*)&part[a2][1][c2*4];
    float4 m2v = *(const float4*)&part[a2][2][c2*4];
    float4 m3v = *(const float4*)&part[a2][3][c2*4];
    int base = a2 ? 160 : 0;   // f at [160,288), fp at [0,128)
    sfin[base + c2*4 + 0] = lrelu(fmaxf(fmaxf(m0v.x, m1v.x), fmaxf(m2v.x, m3v.x)));
    sfin[base + c2*4 + 1] = lrelu(fmaxf(fmaxf(m0v.y, m1v.y), fmaxf(m2v.y, m3v.y)));
    sfin[base + c2*4 + 2] = lrelu(fmaxf(fmaxf(m0v.z, m1v.z), fmaxf(m2v.z, m3v.z)));
    sfin[base + c2*4 + 3] = lrelu(fmaxf(fmaxf(m0v.w, m1v.w), fmaxf(m2v.w, m3v.w)));
  } else if (tid < 192) {
    int c = tid - 64;
    sfin[288 + c] = lrelu(pf[n*128 + c]);       // pf [288,416)
  } else if (tid < 224) {
    int c = tid - 192;
    sfin[128 + c] = lrelu(feat[n*32 + c]);      // feat [128,160)
  }
  __syncthreads();
  if (tid < 104) {
    int plane = tid >= 52;
    int ck = plane ? tid - 52 : tid;
    int ks = ck >> 2, qq = ck & 3;
    int c0 = ks*32 + qq*8;
    short8 o8;
#pragma unroll
    for (int j = 0; j < 8; ++j) {
      unsigned short hh, ll; split2(sfin[c0 + j], hh, ll);
      o8[j] = (short)(plane ? ll : hh);
    }
    size_t pos = (((size_t)(n >> 4)*13 + ks)*64 + qq*16 + (n & 15))*8;
    *(short8*)((plane ? finl : finh) + pos) = o8;
  }
}

// ---------------- final GEMM (K=416, Kc=13, N=128) -> swizzled fused planes ----
__global__ __launch_bounds__(256) void k_final(const unsigned short* __restrict__ Ah,
                                              const unsigned short* __restrict__ Al,
                                              const unsigned short* __restrict__ Wh,
                                              const unsigned short* __restrict__ Wl,
                                              const float* __restrict__ bias,
                                              unsigned short* __restrict__ Ch,
                                              unsigned short* __restrict__ Cl) {
  __shared__ float sC[16][132];
  int tid = threadIdx.x, lane = tid & 63, w = tid >> 6;
  int mr = lane & 15, q = lane >> 4;
  int mt = blockIdx.x;
  f32x4 acc[2];
#pragma unroll
  for (int t = 0; t < 2; ++t) { f32x4 z = {0.f,0.f,0.f,0.f}; acc[t] = z; }
#pragma unroll
  for (int ks = 0; ks < 13; ++ks) {
    int ab = ((mt*13 + ks)*64 + lane)*8;
    short8 ah = *(const short8*)(Ah + ab);
    short8 al = *(const short8*)(Al + ab);
#pragma unroll
    for (int tt = 0; tt < 2; ++tt) {
      int wb = (((2*w+tt)*13 + ks)*64 + lane)*8;
      mfma3(acc[tt], ah, al, *(const short8*)(Wh + wb), *(const short8*)(Wl + wb));
    }
  }
#pragma unroll
  for (int tt = 0; tt < 2; ++tt) {
    int n = (2*w+tt)*16 + mr;
    float b = bias[n];
#pragma unroll
    for (int r = 0; r < 4; ++r) sC[q*4 + r][n] = acc[tt][r] + b;
  }
  __syncthreads();
  {
    int ks = tid >> 6, q2 = (tid >> 4) & 3, mr2 = tid & 15;
    int c0 = ks*32 + q2*8;
    short8 oh, ol;
#pragma unroll
    for (int j = 0; j < 8; ++j) {
      unsigned short hh, ll; split2(sC[mr2][c0 + j], hh, ll);
      oh[j] = (short)hh; ol[j] = (short)ll;
    }
    size_t pos = ((size_t)mt*256 + tid)*8;
    *(short8*)(Ch + pos) = oh;
    *(short8*)(Cl + pos) = ol;
  }
}

// ---------------- conv3+head (blocks<512) | g-reduce+kp MLP (blocks 512..543) --
__global__ __launch_bounds__(256) void k_c3head(const unsigned short* __restrict__ Ah,
                                               const unsigned short* __restrict__ Al,
                                               const unsigned short* __restrict__ Wh,
                                               const unsigned short* __restrict__ Wl,
                                               const float* __restrict__ biasc,
                                               const float* __restrict__ bias2c,
                                               const float* __restrict__ segw, const float* __restrict__ segb,
                                               const float* __restrict__ disw, const float* __restrict__ disb,
                                               float* __restrict__ osegp, float* __restrict__ odisp,
                                               const float* __restrict__ dc,
                                               const float* __restrict__ seg,
                                               float* __restrict__ g,
                                               const float* __restrict__ l1w, const float* __restrict__ l1b,
                                               const float* __restrict__ l2w, const float* __restrict__ l2b,
                                               const float* __restrict__ l3w, const float* __restrict__ l3b,
                                               float* __restrict__ o_kp) {
  int tid = threadIdx.x, lane = tid & 63, w = tid >> 6;
  int mr = lane & 15, q = lane >> 4;
  if (blockIdx.x >= 512) {
    // ---- g = sum_n fused[n]*dc[n]*seg[n] over 16 m-tiles, then gated kp MLP ---
    __shared__ float sred[2048];
    __shared__ int slast;
    int b = blockIdx.x - 512;
    float pg[8] = {0.f,0.f,0.f,0.f,0.f,0.f,0.f,0.f};
    int mrr = tid & 15;
    for (int mi = 0; mi < 16; ++mi) {
      int m = b*16 + mi;
      int row = m*16 + mrr;
      float wrow = dc[row] * seg[row];
      size_t pos = ((size_t)m*256 + tid)*8;
      short8 hv = *(const short8*)(Ah + pos);
      short8 lv = *(const short8*)(Al + pos);
#pragma unroll
      for (int j = 0; j < 8; ++j)
        pg[j] += (bf2f((unsigned short)hv[j]) + bf2f((unsigned short)lv[j])) * wrow;
    }
#pragma unroll
    for (int j = 0; j < 8; ++j) sred[tid*8 + j] = pg[j];
    __syncthreads();
    if (tid < 128) {
      int ks = tid >> 5, q2 = (tid >> 3) & 3, j = tid & 7;
      float s = 0.f;
#pragma unroll
      for (int mr2 = 0; mr2 < 16; ++mr2) s += sred[((ks<<6) + (q2<<4) + mr2)*8 + j];
      atomicAdd(&g[tid], s);
    }
    __threadfence();
    __syncthreads();
    if (tid == 0) slast = (atomicAdd((int*)(g + 128), 1) == 31);
    __syncthreads();
    if (!slast) return;
    __shared__ float sg[128], s1[90], s2[64];
    if (tid < 128) sg[tid] = atomicAdd(&g[tid], 0.f);
    __syncthreads();
    if (tid < 90) {
      float a = l1b[tid];
      for (int i = 0; i < 128; ++i) a += sg[i]*l1w[tid*128+i];
      s1[tid] = lrelu(a);
    }
    __syncthreads();
    if (tid < 64) {
      float a = l2b[tid];
      for (int i = 0; i < 90; ++i) a += s1[i]*l2w[tid*90+i];
      s2[tid] = lrelu(a);
    }
    __syncthreads();
    if (tid < 24) {
      float a = l3b[tid];
      for (int i = 0; i < 64; ++i) a += s2[i]*l3w[tid*64+i];
      o_kp[tid] = a;
    }
    return;
  }
  __shared__ unsigned short t1h[2048], t1l[2048];
  __shared__ float shead[4][16][17];
  int m0 = blockIdx.x * 16;
  // conv3 (K=384 via taps, A swizzled with Kc=4 per row), wave w -> t {2w,2w+1}
  f32x4 acc[2];
#pragma unroll
  for (int t = 0; t < 2; ++t) { f32x4 z = {0.f,0.f,0.f,0.f}; acc[t] = z; }
  const unsigned short* W3h = Wh + OFF_W3;
  const unsigned short* W3l = Wl + OFF_W3;
#pragma unroll
  for (int ks = 0; ks < 12; ++ks) {
    int tap = ks >> 2, ksA = ks & 3;
    int ar = m0 + mr + tap - 1;
    short8 ah = {0,0,0,0,0,0,0,0}, al = {0,0,0,0,0,0,0,0};
    if (ar >= 0 && ar < NPT) {
      int ab = ((((ar >> 4)*4) + ksA)*64 + q*16 + (ar & 15))*8;
      ah = *(const short8*)(Ah + ab);
      al = *(const short8*)(Al + ab);
    }
#pragma unroll
    for (int tt = 0; tt < 2; ++tt) {
      int wb = (((2*w+tt)*12 + ks)*64 + lane)*8;
      mfma3(acc[tt], ah, al, *(const short8*)(W3h + wb), *(const short8*)(W3l + wb));
    }
  }
#pragma unroll
  for (int tt = 0; tt < 2; ++tt) {
    int t2 = 2*w + tt, n = t2*16 + mr;
    float b = biasc[n];
    int ks2 = t2 >> 1, q2 = (t2 & 1)*2 + (mr >> 3), jd = mr & 7;
#pragma unroll
    for (int r = 0; r < 4; ++r) {
      int row = q*4 + r;
      float v = lrelu(acc[tt][r] + b);
      unsigned short hh, ll; split2(v, hh, ll);
      int p = ((ks2*16 + row)*4 + q2)*8 + jd;
      t1h[p] = hh; t1l[p] = ll;
    }
  }
  __syncthreads();
  // head GEMM (K=128, Kc=4, N=64 block-diag), wave w -> t = w
  f32x4 acc2 = {0.f,0.f,0.f,0.f};
  const unsigned short* WPh = Wh + OFF_W2P;
  const unsigned short* WPl = Wl + OFF_W2P;
#pragma unroll
  for (int ks = 0; ks < 4; ++ks) {
    int ap = ((ks*16 + mr)*4 + q)*8;
    short8 ah = *(const short8*)&t1h[ap];
    short8 al = *(const short8*)&t1l[ap];
    int wb = ((w*4 + ks)*64 + lane)*8;
    mfma3(acc2, ah, al, *(const short8*)(WPh + wb), *(const short8*)(WPl + wb));
  }
  float hw = (w < 2) ? segw[w*16 + mr] : disw[(w-2)*16 + mr];
  float bb = bias2c[w*16 + mr];
#pragma unroll
  for (int r = 0; r < 4; ++r)
    shead[w][q*4 + r][mr] = lrelu(acc2[r] + bb) * hw;
  __syncthreads();
  if (tid < 16) {
    float a = 0.f;
#pragma unroll
    for (int i = 0; i < 16; ++i) a += shead[0][tid][i] + shead[1][tid][i];
    osegp[m0 + tid] = a + segb[0];
  } else if (tid < 32) {
    float a = 0.f;
#pragma unroll
    for (int i = 0; i < 16; ++i) a += shead[2][tid-16][i] + shead[3][tid-16][i];
    odisp[m0 + tid - 16] = a + disb[0];
  }
}

extern "C" void kernel_launch(void* const* d_in, const int* in_sizes, int n_in,
                              void* d_out, int out_size, void* d_ws, size_t ws_size,
                              hipStream_t stream) {
  const float* seg      = (const float*)d_in[0];
  const float* img      = (const float*)d_in[1];
  const float* cloud    = (const float*)d_in[2];
  const float* tvec     = (const float*)d_in[3];
  const int*   choose   = (const int*)d_in[4];
  const float* pconv1_w = (const float*)d_in[5];
  const float* pconv1_b = (const float*)d_in[6];
  const float* pconv2_w = (const float*)d_in[7];
  const float* pconv2_b = (const float*)d_in[8];
  const float* conv1_w  = (const float*)d_in[9];
  const float* conv1_b  = (const float*)d_in[10];
  const float* conv2_w  = (const float*)d_in[11];
  const float* conv2_b  = (const float*)d_in[12];
  const float* psconv1_w= (const float*)d_in[13];
  const float* psconv1_b= (const float*)d_in[14];
  const float* psconv2_w= (const float*)d_in[15];
  const float* psconv2_b= (const float*)d_in[16];
  const float* final_w  = (const float*)d_in[17];
  const float* final_b  = (const float*)d_in[18];
  const float* seg1_w   = (const float*)d_in[19];
  const float* seg1_b   = (const float*)d_in[20];
  const float* seg2_w   = (const float*)d_in[21];
  const float* seg2_b   = (const float*)d_in[22];
  const float* seg3_w   = (const float*)d_in[23];
  const float* seg3_b   = (const float*)d_in[24];
  const float* dis1_w   = (const float*)d_in[25];
  const float* dis1_b   = (const float*)d_in[26];
  const float* dis2_w   = (const float*)d_in[27];
  const float* dis2_b   = (const float*)d_in[28];
  const float* dis3_w   = (const float*)d_in[29];
  const float* dis3_b   = (const float*)d_in[30];
  const float* lin1_w   = (const float*)d_in[31];
  const float* lin1_b   = (const float*)d_in[32];
  const float* lin2_w   = (const float*)d_in[33];
  const float* lin2_b   = (const float*)d_in[34];
  const float* lin3_w   = (const float*)d_in[35];
  const float* lin3_b   = (const float*)d_in[36];

  float* out = (float*)d_out;
  float* ws  = (float*)d_ws;

  // workspace layout (float offsets)
  float* c4     = ws + 0;          // 32768
  float* feat   = ws + 32768;      // 262144
  unsigned short* feat_h = (unsigned short*)(ws + 294912);   // 131072 f
  unsigned short* feat_l = (unsigned short*)(ws + 425984);   // 131072 f
  float* pf     = ws + 557056;     // 1048576
  float* Yf     = ws + 1605632;    // 1048576
  float* Yfp    = ws + 2654208;    // 1048576
  int*   idx    = (int*)(ws + 3702784);   // 262144
  float* wsm    = ws + 3964928;    // 262144
  unsigned short* finh  = (unsigned short*)(ws + 4227072);   // 1703936 f
  unsigned short* finl  = (unsigned short*)(ws + 5931008);   // 1703936 f
  unsigned short* fusedh = (unsigned short*)(ws + 8683520);  // 524288 f
  unsigned short* fusedl = (unsigned short*)(ws + 9207808);  // 524288 f
  unsigned short* Wh    = (unsigned short*)(ws + 9732096);   // 97280 f
  unsigned short* Wl    = (unsigned short*)(ws + 9829376);   // 97280 f
  float* biasc  = ws + 9926656;    // 128
  float* bias2c = ws + 9926784;    // 64
  float* g      = ws + 9926848;    // 129 (g[128] = block counter)

  float* o_kp   = out;             // 24
  float* o_disp = out + 24;        // 8192
  float* o_dc   = out + 8216;      // 8192
  float* o_segp = out + 16408;     // 8192

  k_prep0<<<(NPT + 129 + 255)/256, 256, 0, stream>>>(cloud, c4, g);

  k_mega<<<MEGA_GRID, 256, 0, stream>>>(
      (const float4*)c4, idx, wsm, cloud, tvec, o_dc,
      choose, img, seg1_w, dis1_w, seg1_b, dis1_b,
      seg2_w, dis2_w, seg2_b, dis2_b,
      pconv2_w, conv1_w, conv2_w, psconv1_w, psconv2_w, final_w,
      biasc, bias2c, feat, feat_h, feat_l, Wh, Wl);

  k_chain<<<1024, 256, 0, stream>>>(
      (const float4*)c4, pconv1_w, pconv1_b, pconv2_b, psconv1_b, psconv2_b,
      feat_h, feat_l, conv1_b, conv2_b, Wh, Wl, pf, Yfp, Yf);

  k_pool<<<NPT, 256, 0, stream>>>(Yf, Yfp, feat, pf, idx, wsm, finh, finl);

  k_final<<<512, 256, 0, stream>>>(finh, finl, Wh + OFF_FINAL, Wl + OFF_FINAL,
                                   final_b, fusedh, fusedl);

  k_c3head<<<544, 256, 0, stream>>>(fusedh, fusedl, Wh, Wl, biasc, bias2c,
                                    seg3_w, seg3_b, dis3_w, dis3_b, o_segp, o_disp,
                                    o_dc, seg, g,
                                    lin1_w, lin1_b, lin2_w, lin2_b, lin3_w, lin3_b, o_kp);

  (void)in_sizes; (void)n_in; (void)out_size; (void)ws_size;
}

// Round 9
// 238.479 us; speedup vs baseline: 1.3563x; 1.0237x over previous
//
#include <hip/hip_runtime.h>
#include <math.h>

#define NPT 8192
#define HWIMG 19200
#define KCAP 128

using short8 = __attribute__((ext_vector_type(8))) short;
using f32x4  = __attribute__((ext_vector_type(4))) float;

__device__ __forceinline__ float lrelu(float x) { return x > 0.f ? x : 0.01f * x; }
__device__ __forceinline__ unsigned short f2bf(float v) {
  unsigned u = __float_as_uint(v);
  return (unsigned short)((u + 0x7fffu + ((u >> 16) & 1u)) >> 16);
}
__device__ __forceinline__ float bf2f(unsigned short h) {
  return __uint_as_float(((unsigned)h) << 16);
}
__device__ __forceinline__ void split2(float v, unsigned short& h, unsigned short& l) {
  h = f2bf(v);
  l = f2bf(v - bf2f(h));
}
__device__ __forceinline__ void mfma3(f32x4& acc, short8 ah, short8 al, short8 wh, short8 wl) {
  acc = __builtin_amdgcn_mfma_f32_16x16x32_bf16(ah, wh, acc, 0, 0, 0);
  acc = __builtin_amdgcn_mfma_f32_16x16x32_bf16(al, wh, acc, 0, 0, 0);
  acc = __builtin_amdgcn_mfma_f32_16x16x32_bf16(ah, wl, acc, 0, 0, 0);
}

// fragment-sequential swizzle: element (row o, k) of a [N,K] matrix lives at
// chunk ((o/16)*Kc + k/32)*64 + (k/8)%4*16 + o%16, byte-offset k%8.
__device__ __forceinline__ int swz(int o, int k, int Kc) {
  return ((((o >> 4) * Kc + (k >> 5)) << 6) + (((k >> 3) & 3) << 4) + (o & 15)) * 8 + (k & 7);
}

// weight-plane segment offsets (in shorts)
#define OFF_PCONV2  0
#define OFF_CONV1   8192
#define OFF_CONV2   10240
#define OFF_PSCONV1 18432
#define OFF_PSCONV2 51200
#define OFF_FINAL   83968
#define OFF_W3      137216
#define OFF_W2P     186368

// ---------------- prep: everything input-only (c4, feat, weights, biases) ------
#define S_C4    NPT
#define S_G     129
#define S_BIASC 128
#define S_B2C   64
#define S_FEAT  (NPT*32)
#define S_W3    49152
#define S_W2P   8192
#define S_WSPL  OFF_W3
#define PREP_TOTAL (S_C4 + S_G + S_BIASC + S_B2C + S_FEAT + S_W3 + S_W2P + S_WSPL)
__global__ void k_prep(const float* __restrict__ cloud, const int* __restrict__ choose,
                       const float* __restrict__ img,
                       const float* __restrict__ seg1_w, const float* __restrict__ dis1_w,
                       const float* __restrict__ seg1_b, const float* __restrict__ dis1_b,
                       const float* __restrict__ seg2_w, const float* __restrict__ dis2_w,
                       const float* __restrict__ seg2_b, const float* __restrict__ dis2_b,
                       const float* __restrict__ pconv2_w, const float* __restrict__ conv1_w,
                       const float* __restrict__ conv2_w, const float* __restrict__ psconv1_w,
                       const float* __restrict__ psconv2_w, const float* __restrict__ final_w,
                       float* __restrict__ c4, float* __restrict__ g,
                       float* __restrict__ biasc, float* __restrict__ bias2c,
                       float* __restrict__ feat,
                       unsigned short* __restrict__ feat_h, unsigned short* __restrict__ feat_l,
                       unsigned short* __restrict__ Wh, unsigned short* __restrict__ Wl) {
  int j = blockIdx.x * blockDim.x + threadIdx.x;
  if (j < S_C4) {
    float x = cloud[j*3+0], y = cloud[j*3+1], z = cloud[j*3+2];
    float4 v; v.x = x; v.y = y; v.z = z; v.w = x*x + y*y + z*z;
    ((float4*)c4)[j] = v;
    return;
  }
  j -= S_C4;
  if (j < S_G) { g[j] = 0.f; return; }
  j -= S_G;
  if (j < S_BIASC) { biasc[j] = (j < 64) ? seg1_b[j] : dis1_b[j-64]; return; }
  j -= S_BIASC;
  if (j < S_B2C) { bias2c[j] = (j < 32) ? seg2_b[j] : dis2_b[j-32]; return; }
  j -= S_B2C;
  if (j < S_FEAT) {
    int n = j >> 5, ch = j & 31;
    float v = img[ch*HWIMG + choose[n]];
    feat[j] = v;
    unsigned short hh, ll; split2(v, hh, ll);
    int d = swz(n, ch, 1);
    feat_h[d] = hh; feat_l[d] = ll;
    return;
  }
  j -= S_FEAT;
  if (j < S_W3) {                          // conv3 weight transpose + split
    int h = j / 24576, r = j - h*24576, o = r / 384, k = r - o*384;
    int t = k >> 7, c = k & 127;
    float v = (h ? dis1_w : seg1_w)[o*384 + c*3 + t];
    unsigned short hh, ll; split2(v, hh, ll);
    int d = OFF_W3 + swz(h*64 + o, k, 12);
    Wh[d] = hh; Wl[d] = ll;
    return;
  }
  j -= S_W3;
  if (j < S_W2P) {                         // W2p block-diagonal + split
    int o = j >> 7, c = j & 127;
    float v = 0.f;
    if (o < 32) { if (c < 64) v = seg2_w[o*64 + c]; }
    else        { if (c >= 64) v = dis2_w[(o-32)*64 + (c-64)]; }
    unsigned short hh, ll; split2(v, hh, ll);
    int d = OFF_W2P + swz(o, c, 4);
    Wh[d] = hh; Wl[d] = ll;
    return;
  }
  j -= S_W2P;
  if (j < S_WSPL) {                        // weight split (swizzled)
    float v; int d;
    if (j < OFF_CONV1) {
      int o = j >> 6, k = j & 63;
      v = pconv2_w[j]; d = OFF_PCONV2 + swz(o, k, 2);
    } else if (j < OFF_CONV2) {
      int jj = j - OFF_CONV1, o = jj >> 5, k = jj & 31;
      v = conv1_w[jj]; d = OFF_CONV1 + swz(o, k, 1);
    } else if (j < OFF_PSCONV1) {
      int jj = j - OFF_CONV2, o = jj >> 6, k = jj & 63;
      v = conv2_w[jj]; d = OFF_CONV2 + swz(o, k, 2);
    } else if (j < OFF_PSCONV2) {
      int jj = j - OFF_PSCONV1, o = jj >> 7, k = jj & 127;
      v = psconv1_w[jj]; d = OFF_PSCONV1 + swz(o, k, 4);
    } else if (j < OFF_FINAL) {
      int jj = j - OFF_PSCONV2, o = jj >> 8, k = jj & 255;
      v = psconv2_w[jj]; d = OFF_PSCONV2 + swz(o, k, 8);
    } else {
      int jj = j - OFF_FINAL, o = jj / 416, k = jj - o*416;
      v = final_w[jj]; d = OFF_FINAL + swz(o, k, 13);
    }
    unsigned short hh, ll; split2(v, hh, ll);
    Wh[d] = hh; Wl[d] = ll;
  }
}

// ---------------- bitonic helpers ---------------------------------------------
__device__ __forceinline__ unsigned bsort32u(unsigned key, int lane) {
#pragma unroll
  for (int k = 2; k <= 64; k <<= 1) {
#pragma unroll
    for (int j = k >> 1; j > 0; j >>= 1) {
      unsigned o = __shfl_xor(key, j, 64);
      bool keepmin = (((lane & j) == 0) == ((lane & k) == 0));
      key = ((o < key) == keepmin) ? o : key;
    }
  }
  return key;
}
__device__ __forceinline__ unsigned long long bsort64(unsigned long long key, int lane) {
#pragma unroll
  for (int k = 2; k <= 64; k <<= 1) {
#pragma unroll
    for (int j = k >> 1; j > 0; j >>= 1) {
      unsigned long long o = __shfl_xor(key, j, 64);
      bool keepmin = (((lane & j) == 0) == ((lane & k) == 0));
      bool omin = o < key;
      key = (omin == keepmin) ? o : key;
    }
  }
  return key;
}
__device__ __forceinline__ unsigned long long bmerge64(unsigned long long key, int lane) {
#pragma unroll
  for (int j = 32; j > 0; j >>= 1) {
    unsigned long long o = __shfl_xor(key, j, 64);
    bool keepmin = ((lane & j) == 0);
    bool omin = o < key;
    key = (omin == keepmin) ? o : key;
  }
  return key;
}

// ---------------- mega: knn (0..2047) | dc (2048) | MLP chains (2049..3072) ----
// knn is VALU-bound, chain is MFMA-bound: separate pipes co-schedule (overlap).
#define MEGA_GRID 3073
__global__ __launch_bounds__(256) void k_mega(const float4* __restrict__ c4,
                                              int* __restrict__ idxo, float* __restrict__ wo,
                                              const float* __restrict__ cloud,
                                              const float* __restrict__ tvec,
                                              float* __restrict__ dc,
                                              const float* __restrict__ pconv1_w, const float* __restrict__ pconv1_b,
                                              const float* __restrict__ pconv2_b, const float* __restrict__ psconv1_b,
                                              const float* __restrict__ psconv2_b,
                                              const unsigned short* __restrict__ feat_h,
                                              const unsigned short* __restrict__ feat_l,
                                              const float* __restrict__ conv1_b, const float* __restrict__ conv2_b,
                                              const unsigned short* __restrict__ Wh,
                                              const unsigned short* __restrict__ Wl,
                                              float* __restrict__ pf, float* __restrict__ Yfp,
                                              float* __restrict__ Yf) {
  __shared__ __align__(16) char smem[24704];
  int tid = threadIdx.x, lane = tid & 63, w = tid >> 6;
  int mr = lane & 15, q = lane >> 4;
  if (blockIdx.x > 2048) {
    // ================= MLP chains (identical to R8 k_chain) ===================
    unsigned short* sh_h = (unsigned short*)smem;
    unsigned short* sh_l = (unsigned short*)(smem + 12288);
    int cb = blockIdx.x - 2049;
    if (cb < 512) {
      int m0 = cb * 16;
      float4 cp = c4[m0 + mr];
      short8 ah0, al0, ah1, al1;
#pragma unroll
      for (int j = 0; j < 8; ++j) {
        int c0 = q*8 + j, c1 = 32 + q*8 + j;
        float v0 = lrelu(fmaf(cp.x, pconv1_w[c0*3+0], fmaf(cp.y, pconv1_w[c0*3+1],
                          fmaf(cp.z, pconv1_w[c0*3+2], pconv1_b[c0]))));
        float v1 = lrelu(fmaf(cp.x, pconv1_w[c1*3+0], fmaf(cp.y, pconv1_w[c1*3+1],
                          fmaf(cp.z, pconv1_w[c1*3+2], pconv1_b[c1]))));
        unsigned short hh, ll;
        split2(v0, hh, ll); ah0[j] = (short)hh; al0[j] = (short)ll;
        split2(v1, hh, ll); ah1[j] = (short)hh; al1[j] = (short)ll;
      }
      f32x4 acc[2];
#pragma unroll
      for (int t = 0; t < 2; ++t) { f32x4 z = {0.f,0.f,0.f,0.f}; acc[t] = z; }
      const unsigned short* W2h = Wh + OFF_PCONV2;
      const unsigned short* W2l = Wl + OFF_PCONV2;
#pragma unroll
      for (int tt = 0; tt < 2; ++tt) {
        int t1 = 2*w + tt;
        int w0 = ((t1*2 + 0)*64 + lane)*8, w1 = ((t1*2 + 1)*64 + lane)*8;
        mfma3(acc[tt], ah0, al0, *(const short8*)(W2h + w0), *(const short8*)(W2l + w0));
        mfma3(acc[tt], ah1, al1, *(const short8*)(W2h + w1), *(const short8*)(W2l + w1));
      }
#pragma unroll
      for (int tt = 0; tt < 2; ++tt) {
        int t1 = 2*w + tt, n = t1*16 + mr;
        float b = pconv2_b[n];
        int ks2 = t1 >> 1, q2 = (t1 & 1)*2 + (mr >> 3), jd = mr & 7;
#pragma unroll
        for (int r = 0; r < 4; ++r) {
          int row = q*4 + r;
          float v = acc[tt][r] + b;
          pf[(size_t)(m0+row)*128 + n] = v;
          unsigned short hh, ll; split2(v, hh, ll);
          int p = ((ks2*16 + row)*4 + q2)*8 + jd;
          sh_h[p] = hh; sh_l[p] = ll;
        }
      }
      __syncthreads();
      f32x4 acc2[4];
#pragma unroll
      for (int t = 0; t < 4; ++t) { f32x4 z = {0.f,0.f,0.f,0.f}; acc2[t] = z; }
      const unsigned short* W3h = Wh + OFF_PSCONV1;
      const unsigned short* W3l = Wl + OFF_PSCONV1;
#pragma unroll
      for (int ks = 0; ks < 4; ++ks) {
        int ap = ((ks*16 + mr)*4 + q)*8;
        short8 ah = *(const short8*)&sh_h[ap];
        short8 al = *(const short8*)&sh_l[ap];
#pragma unroll
        for (int tt = 0; tt < 4; ++tt) {
          int wb = (((4*w+tt)*4 + ks)*64 + lane)*8;
          mfma3(acc2[tt], ah, al, *(const short8*)(W3h + wb), *(const short8*)(W3l + wb));
        }
      }
      __syncthreads();
#pragma unroll
      for (int tt = 0; tt < 4; ++tt) {
        int t2 = 4*w + tt, n = t2*16 + mr;
        float b = psconv1_b[n];
        int ks3 = t2 >> 1, q3 = (t2 & 1)*2 + (mr >> 3), jd = mr & 7;
#pragma unroll
        for (int r = 0; r < 4; ++r) {
          int row = q*4 + r;
          float v = lrelu(acc2[tt][r] + b);
          unsigned short hh, ll; split2(v, hh, ll);
          int p = 6144 + ((ks3*16 + row)*4 + q3)*8 + jd;
          sh_h[p] = hh; sh_l[p] = ll;
        }
      }
      __syncthreads();
      f32x4 acc3[2];
#pragma unroll
      for (int t = 0; t < 2; ++t) { f32x4 z = {0.f,0.f,0.f,0.f}; acc3[t] = z; }
      const unsigned short* W4h = Wh + OFF_PSCONV2;
      const unsigned short* W4l = Wl + OFF_PSCONV2;
#pragma unroll
      for (int ks = 0; ks < 8; ++ks) {
        int ap = 6144 + ((ks*16 + mr)*4 + q)*8;
        short8 ah = *(const short8*)&sh_h[ap];
        short8 al = *(const short8*)&sh_l[ap];
#pragma unroll
        for (int tt = 0; tt < 2; ++tt) {
          int wb = (((2*w+tt)*8 + ks)*64 + lane)*8;
          mfma3(acc3[tt], ah, al, *(const short8*)(W4h + wb), *(const short8*)(W4l + wb));
        }
      }
#pragma unroll
      for (int tt = 0; tt < 2; ++tt) {
        int n = (2*w+tt)*16 + mr;
        float b = psconv2_b[n];
#pragma unroll
        for (int r = 0; r < 4; ++r)
          Yfp[(size_t)(m0 + q*4 + r)*128 + n] = acc3[tt][r] + b;
      }
    } else {
      int m0 = (cb - 512) * 16;
      int ab = ((m0 >> 4)*64 + lane)*8;
      short8 ah = *(const short8*)(feat_h + ab);
      short8 al = *(const short8*)(feat_l + ab);
      f32x4 acc = {0.f,0.f,0.f,0.f};
      const unsigned short* W1h = Wh + OFF_CONV1;
      const unsigned short* W1l = Wl + OFF_CONV1;
      {
        int wb = (w*64 + lane)*8;
        mfma3(acc, ah, al, *(const short8*)(W1h + wb), *(const short8*)(W1l + wb));
      }
      {
        int n = w*16 + mr;
        float b = conv1_b[n];
        int ks2 = n >> 5, q2 = (n >> 3) & 3, jd = mr & 7;
#pragma unroll
        for (int r = 0; r < 4; ++r) {
          int row = q*4 + r;
          float v = lrelu(acc[r] + b);
          unsigned short hh, ll; split2(v, hh, ll);
          int p = ((ks2*16 + row)*4 + q2)*8 + jd;
          sh_h[p] = hh; sh_l[p] = ll;
        }
      }
      __syncthreads();
      f32x4 acc2[2];
#pragma unroll
      for (int t = 0; t < 2; ++t) { f32x4 z = {0.f,0.f,0.f,0.f}; acc2[t] = z; }
      const unsigned short* W2h = Wh + OFF_CONV2;
      const unsigned short* W2l = Wl + OFF_CONV2;
#pragma unroll
      for (int ks = 0; ks < 2; ++ks) {
        int ap = ((ks*16 + mr)*4 + q)*8;
        short8 a2 = *(const short8*)&sh_h[ap];
        short8 a2l = *(const short8*)&sh_l[ap];
#pragma unroll
        for (int tt = 0; tt < 2; ++tt) {
          int wb = (((2*w+tt)*2 + ks)*64 + lane)*8;
          mfma3(acc2[tt], a2, a2l, *(const short8*)(W2h + wb), *(const short8*)(W2l + wb));
        }
      }
#pragma unroll
      for (int tt = 0; tt < 2; ++tt) {
        int n = (2*w+tt)*16 + mr;
        float b = conv2_b[n];
#pragma unroll
        for (int r = 0; r < 4; ++r)
          Yf[(size_t)(m0 + q*4 + r)*128 + n] = acc2[tt][r] + b;
      }
    }
    return;
  }
  if (blockIdx.x == 2048) {
    // ================= dis_center softmax =====================================
    float* sred = (float*)smem;
    float tx = tvec[0], ty = tvec[1], tz = tvec[2];
    float v[32];
    float m = -INFINITY;
#pragma unroll
    for (int i2 = 0; i2 < 32; ++i2) {
      int n = i2*256 + tid;
      float ax = cloud[n*3+0] + tx, ay = cloud[n*3+1] + ty, az = cloud[n*3+2] + tz;
      v[i2] = sqrtf(ax*ax + ay*ay + az*az);
      m = fmaxf(m, v[i2]);
    }
#pragma unroll
    for (int o = 1; o < 64; o <<= 1) m = fmaxf(m, __shfl_xor(m, o, 64));
    if (lane == 0) sred[w] = m;
    __syncthreads();
    m = fmaxf(fmaxf(sred[0], sred[1]), fmaxf(sred[2], sred[3]));
    __syncthreads();
    float s = 0.f;
#pragma unroll
    for (int i2 = 0; i2 < 32; ++i2) { v[i2] = expf(v[i2] - m); s += v[i2]; }
#pragma unroll
    for (int o = 1; o < 64; o <<= 1) s += __shfl_xor(s, o, 64);
    if (lane == 0) sred[w] = s;
    __syncthreads();
    s = sred[0] + sred[1] + sred[2] + sred[3];
#pragma unroll
    for (int i2 = 0; i2 < 32; ++i2) dc[i2*256 + tid] = v[i2] / s;
    return;
  }
  // ================= knn ======================================================
  float (*smin)[256] = (float(*)[256])smem;                 // 4096 B
  float* sTv = (float*)(smem + 4096);                       // 16 B
  int*   scnt = (int*)(smem + 4112);                        // 16 B
  float (*sd)[KCAP] = (float(*)[KCAP])(smem + 4128);        // 2048 B
  int   (*sj)[KCAP] = (int(*)[KCAP])(smem + 6176);          // 2048 B
  int q0 = blockIdx.x * 4;
  float4 p0 = c4[q0], p1 = c4[q0+1], p2 = c4[q0+2], p3 = c4[q0+3];
  float p0x = -2.f*p0.x, p0y = -2.f*p0.y, p0z = -2.f*p0.z;
  float p1x = -2.f*p1.x, p1y = -2.f*p1.y, p1z = -2.f*p1.z;
  float p2x = -2.f*p2.x, p2y = -2.f*p2.y, p2z = -2.f*p2.z;
  float p3x = -2.f*p3.x, p3y = -2.f*p3.y, p3z = -2.f*p3.z;
#define DDOT(PX,PY,PZ,PW,CJ) fmaf(PX,(CJ).x, fmaf(PY,(CJ).y, fmaf(PZ,(CJ).z, PW + (CJ).w)))
  float m0 = INFINITY, m1 = INFINITY, m2 = INFINITY, m3 = INFINITY;
  for (int t = 0; t < 32; ++t) {
    float4 cj = c4[t*256 + tid];
    m0 = fminf(m0, DDOT(p0x,p0y,p0z,p0.w,cj));
    m1 = fminf(m1, DDOT(p1x,p1y,p1z,p1.w,cj));
    m2 = fminf(m2, DDOT(p2x,p2y,p2z,p2.w,cj));
    m3 = fminf(m3, DDOT(p3x,p3y,p3z,p3.w,cj));
  }
  smin[0][tid] = m0; smin[1][tid] = m1; smin[2][tid] = m2; smin[3][tid] = m3;
  if (tid < 4) scnt[tid] = 0;
  __syncthreads();
  {
    // T_ub = 32nd smallest of 64 per-lane min-of-4s (each lane covers 4 disjoint
    // thread candidate-sets -> the 32 smallest lanes witness 32 distinct
    // candidates <= T). One bitonic sort (21 shfl) replaces 32 extractions.
    float4 vv = *(const float4*)&smin[w][lane*4];
    float m4 = fmaxf(fminf(fminf(vv.x, vv.y), fminf(vv.z, vv.w)), 0.f);
    unsigned key = bsort32u(__float_as_uint(m4), lane);
    float T = __uint_as_float(__shfl(key, 31, 64));
    if (lane == 0) sTv[w] = T * (1.f + 2e-5f) + 4e-5f;   // dot-form error guard
  }
  __syncthreads();
  float T0 = sTv[0], T1 = sTv[1], T2 = sTv[2], T3 = sTv[3];
  for (int t = 0; t < 32; ++t) {
    int j = t*256 + tid;
    float4 cj = c4[j];
    float d;
#define APPEND(Q, P) { \
    float dx_ = (P).x-cj.x, dy_ = (P).y-cj.y, dz_ = (P).z-cj.z; \
    float de_ = dx_*dx_ + dy_*dy_ + dz_*dz_; \
    int p_ = atomicAdd(&scnt[Q],1); if (p_ < KCAP) { sd[Q][p_] = de_; sj[Q][p_] = j; } }
    d = DDOT(p0x,p0y,p0z,p0.w,cj); if (d <= T0) APPEND(0, p0);
    d = DDOT(p1x,p1y,p1z,p1.w,cj); if (d <= T1) APPEND(1, p1);
    d = DDOT(p2x,p2y,p2z,p2.w,cj); if (d <= T2) APPEND(2, p2);
    d = DDOT(p3x,p3y,p3z,p3.w,cj); if (d <= T3) APPEND(3, p3);
  }
  __syncthreads();
  int M = scnt[w]; if (M > KCAP) M = KCAP;
  unsigned long long key = (lane < M)
      ? (((unsigned long long)__float_as_uint(sd[w][lane]) << 32) | (unsigned)sj[w][lane])
      : ~0ull;
  key = bsort64(key, lane);
  for (int base = 64; base < M; base += 64) {
    unsigned long long nk = (base + lane < M)
        ? (((unsigned long long)__float_as_uint(sd[w][base+lane]) << 32) | (unsigned)sj[w][base+lane])
        : ~0ull;
    nk = bsort64(nk, lane);
    nk = __shfl_xor(nk, 63, 64);
    key = key < nk ? key : nk;
    key = bmerge64(key, lane);
  }
  float dsel = __uint_as_float((unsigned)(key >> 32));
  int   jsel = (int)(unsigned)(key & 0xffffffffu);
  float v = -sqrtf(dsel);
  float mx = v;
#pragma unroll
  for (int o = 1; o < 32; o <<= 1) mx = fmaxf(mx, __shfl_xor(mx, o, 64));
  float e = expf(v - mx);
  float s = e;
#pragma unroll
  for (int o = 1; o < 32; o <<= 1) s += __shfl_xor(s, o, 64);
  if (lane < 32) {
    int qd = q0 + w;
    wo[qd*32 + lane] = e / s;
    idxo[qd*32 + lane] = jsel;
  }
}

// ---------------- pool: float4 gathers -> sfin LDS -> 16B swizzled chunks ------
__global__ __launch_bounds__(256) void k_pool(const float* __restrict__ Yf,
                                              const float* __restrict__ Yfp,
                                              const float* __restrict__ feat,
                                              const float* __restrict__ pf,
                                              const int* __restrict__ idx,
                                              const float* __restrict__ w,
                                              unsigned short* __restrict__ finh,
                                              unsigned short* __restrict__ finl) {
  int n = blockIdx.x;
  int tid = threadIdx.x;
  __shared__ int sj[32];
  __shared__ float sw[32];
  __shared__ float part[2][4][128];
  __shared__ float sfin[416];
  if (tid < 32) { sj[tid] = idx[n*32+tid]; sw[tid] = w[n*32+tid]; }
  __syncthreads();
  int arr = tid >> 7, kq = (tid >> 5) & 3, cg = tid & 31;
  const float* Y = arr ? Yf : Yfp;
  float4 acc = {-INFINITY, -INFINITY, -INFINITY, -INFINITY};
#pragma unroll
  for (int kk = 0; kk < 8; ++kk) {
    int k = kq*8 + kk;
    float4 v = *(const float4*)&Y[(size_t)sj[k]*128 + cg*4];
    float wk = sw[k];
    acc.x = fmaxf(acc.x, wk*v.x); acc.y = fmaxf(acc.y, wk*v.y);
    acc.z = fmaxf(acc.z, wk*v.z); acc.w = fmaxf(acc.w, wk*v.w);
  }
  *(float4*)&part[arr][kq][cg*4] = acc;
  __syncthreads();
  if (tid < 64) {
    int a2 = tid >> 5, c2 = tid & 31;
    float4 m0v = *(const float4*)&part[a2][0][c2*4];
    float4 m1v = *(const float4*)&part[a2][1][c2*4];
    float4 m2v = *(const float4*)&part[a2][2][c2*4];
    float4 m3v = *(const float4*)&part[a2][3][c2*4];
    int base = a2 ? 160 : 0;
    sfin[base + c2*4 + 0] = lrelu(fmaxf(fmaxf(m0v.x, m1v.x), fmaxf(m2v.x, m3v.x)));
    sfin[base + c2*4 + 1] = lrelu(fmaxf(fmaxf(m0v.y, m1v.y), fmaxf(m2v.y, m3v.y)));
    sfin[base + c2*4 + 2] = lrelu(fmaxf(fmaxf(m0v.z, m1v.z), fmaxf(m2v.z, m3v.z)));
    sfin[base + c2*4 + 3] = lrelu(fmaxf(fmaxf(m0v.w, m1v.w), fmaxf(m2v.w, m3v.w)));
  } else if (tid < 192) {
    int c = tid - 64;
    sfin[288 + c] = lrelu(pf[n*128 + c]);
  } else if (tid < 224) {
    int c = tid - 192;
    sfin[128 + c] = lrelu(feat[n*32 + c]);
  }
  __syncthreads();
  if (tid < 104) {
    int plane = tid >= 52;
    int ck = plane ? tid - 52 : tid;
    int ks = ck >> 2, qq = ck & 3;
    int c0 = ks*32 + qq*8;
    short8 o8;
#pragma unroll
    for (int j = 0; j < 8; ++j) {
      unsigned short hh, ll; split2(sfin[c0 + j], hh, ll);
      o8[j] = (short)(plane ? ll : hh);
    }
    size_t pos = (((size_t)(n >> 4)*13 + ks)*64 + qq*16 + (n & 15))*8;
    *(short8*)((plane ? finl : finh) + pos) = o8;
  }
}

// ---------------- final GEMM (K=416, Kc=13, N=128) -> swizzled fused planes ----
__global__ __launch_bounds__(256) void k_final(const unsigned short* __restrict__ Ah,
                                              const unsigned short* __restrict__ Al,
                                              const unsigned short* __restrict__ Wh,
                                              const unsigned short* __restrict__ Wl,
                                              const float* __restrict__ bias,
                                              unsigned short* __restrict__ Ch,
                                              unsigned short* __restrict__ Cl) {
  __shared__ float sC[16][132];
  int tid = threadIdx.x, lane = tid & 63, w = tid >> 6;
  int mr = lane & 15, q = lane >> 4;
  int mt = blockIdx.x;
  f32x4 acc[2];
#pragma unroll
  for (int t = 0; t < 2; ++t) { f32x4 z = {0.f,0.f,0.f,0.f}; acc[t] = z; }
#pragma unroll
  for (int ks = 0; ks < 13; ++ks) {
    int ab = ((mt*13 + ks)*64 + lane)*8;
    short8 ah = *(const short8*)(Ah + ab);
    short8 al = *(const short8*)(Al + ab);
#pragma unroll
    for (int tt = 0; tt < 2; ++tt) {
      int wb = (((2*w+tt)*13 + ks)*64 + lane)*8;
      mfma3(acc[tt], ah, al, *(const short8*)(Wh + wb), *(const short8*)(Wl + wb));
    }
  }
#pragma unroll
  for (int tt = 0; tt < 2; ++tt) {
    int n = (2*w+tt)*16 + mr;
    float b = bias[n];
#pragma unroll
    for (int r = 0; r < 4; ++r) sC[q*4 + r][n] = acc[tt][r] + b;
  }
  __syncthreads();
  {
    int ks = tid >> 6, q2 = (tid >> 4) & 3, mr2 = tid & 15;
    int c0 = ks*32 + q2*8;
    short8 oh, ol;
#pragma unroll
    for (int j = 0; j < 8; ++j) {
      unsigned short hh, ll; split2(sC[mr2][c0 + j], hh, ll);
      oh[j] = (short)hh; ol[j] = (short)ll;
    }
    size_t pos = ((size_t)mt*256 + tid)*8;
    *(short8*)(Ch + pos) = oh;
    *(short8*)(Cl + pos) = ol;
  }
}

// ---------------- conv3+head (blocks<512) | g-reduce+kp MLP (512..543) ---------
__global__ __launch_bounds__(256) void k_c3head(const unsigned short* __restrict__ Ah,
                                               const unsigned short* __restrict__ Al,
                                               const unsigned short* __restrict__ Wh,
                                               const unsigned short* __restrict__ Wl,
                                               const float* __restrict__ biasc,
                                               const float* __restrict__ bias2c,
                                               const float* __restrict__ segw, const float* __restrict__ segb,
                                               const float* __restrict__ disw, const float* __restrict__ disb,
                                               float* __restrict__ osegp, float* __restrict__ odisp,
                                               const float* __restrict__ dc,
                                               const float* __restrict__ seg,
                                               float* __restrict__ g,
                                               const float* __restrict__ l1w, const float* __restrict__ l1b,
                                               const float* __restrict__ l2w, const float* __restrict__ l2b,
                                               const float* __restrict__ l3w, const float* __restrict__ l3b,
                                               float* __restrict__ o_kp) {
  int tid = threadIdx.x, lane = tid & 63, w = tid >> 6;
  int mr = lane & 15, q = lane >> 4;
  if (blockIdx.x >= 512) {
    __shared__ float sred[2048];
    __shared__ int slast;
    int b = blockIdx.x - 512;
    float pg[8] = {0.f,0.f,0.f,0.f,0.f,0.f,0.f,0.f};
    int mrr = tid & 15;
    for (int mi = 0; mi < 16; ++mi) {
      int m = b*16 + mi;
      int row = m*16 + mrr;
      float wrow = dc[row] * seg[row];
      size_t pos = ((size_t)m*256 + tid)*8;
      short8 hv = *(const short8*)(Ah + pos);
      short8 lv = *(const short8*)(Al + pos);
#pragma unroll
      for (int j = 0; j < 8; ++j)
        pg[j] += (bf2f((unsigned short)hv[j]) + bf2f((unsigned short)lv[j])) * wrow;
    }
#pragma unroll
    for (int j = 0; j < 8; ++j) sred[tid*8 + j] = pg[j];
    __syncthreads();
    if (tid < 128) {
      int ks = tid >> 5, q2 = (tid >> 3) & 3, j = tid & 7;
      float s = 0.f;
#pragma unroll
      for (int mr2 = 0; mr2 < 16; ++mr2) s += sred[((ks<<6) + (q2<<4) + mr2)*8 + j];
      atomicAdd(&g[tid], s);
    }
    __threadfence();
    __syncthreads();
    if (tid == 0) slast = (atomicAdd((int*)(g + 128), 1) == 31);
    __syncthreads();
    if (!slast) return;
    __shared__ float sg[128], s1[90], s2[64];
    if (tid < 128) sg[tid] = atomicAdd(&g[tid], 0.f);
    __syncthreads();
    if (tid < 90) {
      float a = l1b[tid];
      for (int i = 0; i < 128; ++i) a += sg[i]*l1w[tid*128+i];
      s1[tid] = lrelu(a);
    }
    __syncthreads();
    if (tid < 64) {
      float a = l2b[tid];
      for (int i = 0; i < 90; ++i) a += s1[i]*l2w[tid*90+i];
      s2[tid] = lrelu(a);
    }
    __syncthreads();
    if (tid < 24) {
      float a = l3b[tid];
      for (int i = 0; i < 64; ++i) a += s2[i]*l3w[tid*64+i];
      o_kp[tid] = a;
    }
    return;
  }
  __shared__ unsigned short t1h[2048], t1l[2048];
  __shared__ float shead[4][16][17];
  int m0 = blockIdx.x * 16;
  f32x4 acc[2];
#pragma unroll
  for (int t = 0; t < 2; ++t) { f32x4 z = {0.f,0.f,0.f,0.f}; acc[t] = z; }
  const unsigned short* W3h = Wh + OFF_W3;
  const unsigned short* W3l = Wl + OFF_W3;
#pragma unroll
  for (int ks = 0; ks < 12; ++ks) {
    int tap = ks >> 2, ksA = ks & 3;
    int ar = m0 + mr + tap - 1;
    short8 ah = {0,0,0,0,0,0,0,0}, al = {0,0,0,0,0,0,0,0};
    if (ar >= 0 && ar < NPT) {
      int ab = ((((ar >> 4)*4) + ksA)*64 + q*16 + (ar & 15))*8;
      ah = *(const short8*)(Ah + ab);
      al = *(const short8*)(Al + ab);
    }
#pragma unroll
    for (int tt = 0; tt < 2; ++tt) {
      int wb = (((2*w+tt)*12 + ks)*64 + lane)*8;
      mfma3(acc[tt], ah, al, *(const short8*)(W3h + wb), *(const short8*)(W3l + wb));
    }
  }
#pragma unroll
  for (int tt = 0; tt < 2; ++tt) {
    int t2 = 2*w + tt, n = t2*16 + mr;
    float b = biasc[n];
    int ks2 = t2 >> 1, q2 = (t2 & 1)*2 + (mr >> 3), jd = mr & 7;
#pragma unroll
    for (int r = 0; r < 4; ++r) {
      int row = q*4 + r;
      float v = lrelu(acc[tt][r] + b);
      unsigned short hh, ll; split2(v, hh, ll);
      int p = ((ks2*16 + row)*4 + q2)*8 + jd;
      t1h[p] = hh; t1l[p] = ll;
    }
  }
  __syncthreads();
  f32x4 acc2 = {0.f,0.f,0.f,0.f};
  const unsigned short* WPh = Wh + OFF_W2P;
  const unsigned short* WPl = Wl + OFF_W2P;
#pragma unroll
  for (int ks = 0; ks < 4; ++ks) {
    int ap = ((ks*16 + mr)*4 + q)*8;
    short8 ah = *(const short8*)&t1h[ap];
    short8 al = *(const short8*)&t1l[ap];
    int wb = ((w*4 + ks)*64 + lane)*8;
    mfma3(acc2, ah, al, *(const short8*)(WPh + wb), *(const short8*)(WPl + wb));
  }
  float hw = (w < 2) ? segw[w*16 + mr] : disw[(w-2)*16 + mr];
  float bb = bias2c[w*16 + mr];
#pragma unroll
  for (int r = 0; r < 4; ++r)
    shead[w][q*4 + r][mr] = lrelu(acc2[r] + bb) * hw;
  __syncthreads();
  if (tid < 16) {
    float a = 0.f;
#pragma unroll
    for (int i = 0; i < 16; ++i) a += shead[0][tid][i] + shead[1][tid][i];
    osegp[m0 + tid] = a + segb[0];
  } else if (tid < 32) {
    float a = 0.f;
#pragma unroll
    for (int i = 0; i < 16; ++i) a += shead[2][tid-16][i] + shead[3][tid-16][i];
    odisp[m0 + tid - 16] = a + disb[0];
  }
}

extern "C" void kernel_launch(void* const* d_in, const int* in_sizes, int n_in,
                              void* d_out, int out_size, void* d_ws, size_t ws_size,
                              hipStream_t stream) {
  const float* seg      = (const float*)d_in[0];
  const float* img      = (const float*)d_in[1];
  const float* cloud    = (const float*)d_in[2];
  const float* tvec     = (const float*)d_in[3];
  const int*   choose   = (const int*)d_in[4];
  const float* pconv1_w = (const float*)d_in[5];
  const float* pconv1_b = (const float*)d_in[6];
  const float* pconv2_w = (const float*)d_in[7];
  const float* pconv2_b = (const float*)d_in[8];
  const float* conv1_w  = (const float*)d_in[9];
  const float* conv1_b  = (const float*)d_in[10];
  const float* conv2_w  = (const float*)d_in[11];
  const float* conv2_b  = (const float*)d_in[12];
  const float* psconv1_w= (const float*)d_in[13];
  const float* psconv1_b= (const float*)d_in[14];
  const float* psconv2_w= (const float*)d_in[15];
  const float* psconv2_b= (const float*)d_in[16];
  const float* final_w  = (const float*)d_in[17];
  const float* final_b  = (const float*)d_in[18];
  const float* seg1_w   = (const float*)d_in[19];
  const float* seg1_b   = (const float*)d_in[20];
  const float* seg2_w   = (const float*)d_in[21];
  const float* seg2_b   = (const float*)d_in[22];
  const float* seg3_w   = (const float*)d_in[23];
  const float* seg3_b   = (const float*)d_in[24];
  const float* dis1_w   = (const float*)d_in[25];
  const float* dis1_b   = (const float*)d_in[26];
  const float* dis2_w   = (const float*)d_in[27];
  const float* dis2_b   = (const float*)d_in[28];
  const float* dis3_w   = (const float*)d_in[29];
  const float* dis3_b   = (const float*)d_in[30];
  const float* lin1_w   = (const float*)d_in[31];
  const float* lin1_b   = (const float*)d_in[32];
  const float* lin2_w   = (const float*)d_in[33];
  const float* lin2_b   = (const float*)d_in[34];
  const float* lin3_w   = (const float*)d_in[35];
  const float* lin3_b   = (const float*)d_in[36];

  float* out = (float*)d_out;
  float* ws  = (float*)d_ws;

  // workspace layout (float offsets)
  float* c4     = ws + 0;          // 32768
  float* feat   = ws + 32768;      // 262144
  unsigned short* feat_h = (unsigned short*)(ws + 294912);   // 131072 f
  unsigned short* feat_l = (unsigned short*)(ws + 425984);   // 131072 f
  float* pf     = ws + 557056;     // 1048576
  float* Yf     = ws + 1605632;    // 1048576
  float* Yfp    = ws + 2654208;    // 1048576
  int*   idx    = (int*)(ws + 3702784);   // 262144
  float* wsm    = ws + 3964928;    // 262144
  unsigned short* finh  = (unsigned short*)(ws + 4227072);   // 1703936 f
  unsigned short* finl  = (unsigned short*)(ws + 5931008);   // 1703936 f
  unsigned short* fusedh = (unsigned short*)(ws + 8683520);  // 524288 f
  unsigned short* fusedl = (unsigned short*)(ws + 9207808);  // 524288 f
  unsigned short* Wh    = (unsigned short*)(ws + 9732096);   // 97280 f
  unsigned short* Wl    = (unsigned short*)(ws + 9829376);   // 97280 f
  float* biasc  = ws + 9926656;    // 128
  float* bias2c = ws + 9926784;    // 64
  float* g      = ws + 9926848;    // 129 (g[128] = block counter)

  float* o_kp   = out;             // 24
  float* o_disp = out + 24;        // 8192
  float* o_dc   = out + 8216;      // 8192
  float* o_segp = out + 16408;     // 8192

  k_prep<<<(PREP_TOTAL + 255)/256, 256, 0, stream>>>(
      cloud, choose, img, seg1_w, dis1_w, seg1_b, dis1_b,
      seg2_w, dis2_w, seg2_b, dis2_b,
      pconv2_w, conv1_w, conv2_w, psconv1_w, psconv2_w, final_w,
      c4, g, biasc, bias2c, feat, feat_h, feat_l, Wh, Wl);

  k_mega<<<MEGA_GRID, 256, 0, stream>>>(
      (const float4*)c4, idx, wsm, cloud, tvec, o_dc,
      pconv1_w, pconv1_b, pconv2_b, psconv1_b, psconv2_b,
      feat_h, feat_l, conv1_b, conv2_b, Wh, Wl, pf, Yfp, Yf);

  k_pool<<<NPT, 256, 0, stream>>>(Yf, Yfp, feat, pf, idx, wsm, finh, finl);

  k_final<<<512, 256, 0, stream>>>(finh, finl, Wh + OFF_FINAL, Wl + OFF_FINAL,
                                   final_b, fusedh, fusedl);

  k_c3head<<<544, 256, 0, stream>>>(fusedh, fusedl, Wh, Wl, biasc, bias2c,
                                    seg3_w, seg3_b, dis3_w, dis3_b, o_segp, o_disp,
                                    o_dc, seg, g,
                                    lin1_w, lin1_b, lin2_w, lin2_b, lin3_w, lin3_b, o_kp);

  (void)in_sizes; (void)n_in; (void)out_size; (void)ws_size;
}

// Round 10
// 230.000 us; speedup vs baseline: 1.4063x; 1.0369x over previous
//
#include <hip/hip_runtime.h>
#include <math.h>

#define NPT 8192
#define HWIMG 19200
#define KCAP 128

using short8 = __attribute__((ext_vector_type(8))) short;
using short4v = __attribute__((ext_vector_type(4))) short;
using f32x4  = __attribute__((ext_vector_type(4))) float;

__device__ __forceinline__ float lrelu(float x) { return x > 0.f ? x : 0.01f * x; }
__device__ __forceinline__ unsigned short f2bf(float v) {
  unsigned u = __float_as_uint(v);
  return (unsigned short)((u + 0x7fffu + ((u >> 16) & 1u)) >> 16);
}
__device__ __forceinline__ float bf2f(unsigned short h) {
  return __uint_as_float(((unsigned)h) << 16);
}
__device__ __forceinline__ void split2(float v, unsigned short& h, unsigned short& l) {
  h = f2bf(v);
  l = f2bf(v - bf2f(h));
}
__device__ __forceinline__ void mfma3(f32x4& acc, short8 ah, short8 al, short8 wh, short8 wl) {
  acc = __builtin_amdgcn_mfma_f32_16x16x32_bf16(ah, wh, acc, 0, 0, 0);
  acc = __builtin_amdgcn_mfma_f32_16x16x32_bf16(al, wh, acc, 0, 0, 0);
  acc = __builtin_amdgcn_mfma_f32_16x16x32_bf16(ah, wl, acc, 0, 0, 0);
}

// fragment-sequential swizzle: element (row o, k) of a [N,K] matrix lives at
// chunk ((o/16)*Kc + k/32)*64 + (k/8)%4*16 + o%16, byte-offset k%8.
__device__ __forceinline__ int swz(int o, int k, int Kc) {
  return ((((o >> 4) * Kc + (k >> 5)) << 6) + (((k >> 3) & 3) << 4) + (o & 15)) * 8 + (k & 7);
}

// weight-plane segment offsets (in shorts)
#define OFF_PCONV2  0
#define OFF_CONV1   8192
#define OFF_CONV2   10240
#define OFF_PSCONV1 18432
#define OFF_PSCONV2 51200
#define OFF_FINAL   83968
#define OFF_W3      137216
#define OFF_W2P     186368

// ---------------- prep: everything input-only (c4, feat, weights, biases) ------
#define S_C4    NPT
#define S_G     129
#define S_BIASC 128
#define S_B2C   64
#define S_FEAT  (NPT*32)
#define S_W3    49152
#define S_W2P   8192
#define S_WSPL  OFF_W3
#define PREP_TOTAL (S_C4 + S_G + S_BIASC + S_B2C + S_FEAT + S_W3 + S_W2P + S_WSPL)
__global__ void k_prep(const float* __restrict__ cloud, const int* __restrict__ choose,
                       const float* __restrict__ img,
                       const float* __restrict__ seg1_w, const float* __restrict__ dis1_w,
                       const float* __restrict__ seg1_b, const float* __restrict__ dis1_b,
                       const float* __restrict__ seg2_w, const float* __restrict__ dis2_w,
                       const float* __restrict__ seg2_b, const float* __restrict__ dis2_b,
                       const float* __restrict__ pconv2_w, const float* __restrict__ conv1_w,
                       const float* __restrict__ conv2_w, const float* __restrict__ psconv1_w,
                       const float* __restrict__ psconv2_w, const float* __restrict__ final_w,
                       float* __restrict__ c4, float* __restrict__ g,
                       float* __restrict__ biasc, float* __restrict__ bias2c,
                       float* __restrict__ feat,
                       unsigned short* __restrict__ feat_h, unsigned short* __restrict__ feat_l,
                       unsigned short* __restrict__ Wh, unsigned short* __restrict__ Wl) {
  int j = blockIdx.x * blockDim.x + threadIdx.x;
  if (j < S_C4) {
    float x = cloud[j*3+0], y = cloud[j*3+1], z = cloud[j*3+2];
    float4 v; v.x = x; v.y = y; v.z = z; v.w = x*x + y*y + z*z;
    ((float4*)c4)[j] = v;
    return;
  }
  j -= S_C4;
  if (j < S_G) { g[j] = 0.f; return; }
  j -= S_G;
  if (j < S_BIASC) { biasc[j] = (j < 64) ? seg1_b[j] : dis1_b[j-64]; return; }
  j -= S_BIASC;
  if (j < S_B2C) { bias2c[j] = (j < 32) ? seg2_b[j] : dis2_b[j-32]; return; }
  j -= S_B2C;
  if (j < S_FEAT) {
    int n = j >> 5, ch = j & 31;
    float v = img[ch*HWIMG + choose[n]];
    feat[j] = v;
    unsigned short hh, ll; split2(v, hh, ll);
    int d = swz(n, ch, 1);
    feat_h[d] = hh; feat_l[d] = ll;
    return;
  }
  j -= S_FEAT;
  if (j < S_W3) {                          // conv3 weight transpose + split
    int h = j / 24576, r = j - h*24576, o = r / 384, k = r - o*384;
    int t = k >> 7, c = k & 127;
    float v = (h ? dis1_w : seg1_w)[o*384 + c*3 + t];
    unsigned short hh, ll; split2(v, hh, ll);
    int d = OFF_W3 + swz(h*64 + o, k, 12);
    Wh[d] = hh; Wl[d] = ll;
    return;
  }
  j -= S_W3;
  if (j < S_W2P) {                         // W2p block-diagonal + split
    int o = j >> 7, c = j & 127;
    float v = 0.f;
    if (o < 32) { if (c < 64) v = seg2_w[o*64 + c]; }
    else        { if (c >= 64) v = dis2_w[(o-32)*64 + (c-64)]; }
    unsigned short hh, ll; split2(v, hh, ll);
    int d = OFF_W2P + swz(o, c, 4);
    Wh[d] = hh; Wl[d] = ll;
    return;
  }
  j -= S_W2P;
  if (j < S_WSPL) {                        // weight split (swizzled)
    float v; int d;
    if (j < OFF_CONV1) {
      int o = j >> 6, k = j & 63;
      v = pconv2_w[j]; d = OFF_PCONV2 + swz(o, k, 2);
    } else if (j < OFF_CONV2) {
      int jj = j - OFF_CONV1, o = jj >> 5, k = jj & 31;
      v = conv1_w[jj]; d = OFF_CONV1 + swz(o, k, 1);
    } else if (j < OFF_PSCONV1) {
      int jj = j - OFF_CONV2, o = jj >> 6, k = jj & 63;
      v = conv2_w[jj]; d = OFF_CONV2 + swz(o, k, 2);
    } else if (j < OFF_PSCONV2) {
      int jj = j - OFF_PSCONV1, o = jj >> 7, k = jj & 127;
      v = psconv1_w[jj]; d = OFF_PSCONV1 + swz(o, k, 4);
    } else if (j < OFF_FINAL) {
      int jj = j - OFF_PSCONV2, o = jj >> 8, k = jj & 255;
      v = psconv2_w[jj]; d = OFF_PSCONV2 + swz(o, k, 8);
    } else {
      int jj = j - OFF_FINAL, o = jj / 416, k = jj - o*416;
      v = final_w[jj]; d = OFF_FINAL + swz(o, k, 13);
    }
    unsigned short hh, ll; split2(v, hh, ll);
    Wh[d] = hh; Wl[d] = ll;
  }
}

// ---------------- bitonic helpers ---------------------------------------------
__device__ __forceinline__ unsigned bsort32u(unsigned key, int lane) {
#pragma unroll
  for (int k = 2; k <= 64; k <<= 1) {
#pragma unroll
    for (int j = k >> 1; j > 0; j >>= 1) {
      unsigned o = __shfl_xor(key, j, 64);
      bool keepmin = (((lane & j) == 0) == ((lane & k) == 0));
      key = ((o < key) == keepmin) ? o : key;
    }
  }
  return key;
}
__device__ __forceinline__ unsigned long long bsort64(unsigned long long key, int lane) {
#pragma unroll
  for (int k = 2; k <= 64; k <<= 1) {
#pragma unroll
    for (int j = k >> 1; j > 0; j >>= 1) {
      unsigned long long o = __shfl_xor(key, j, 64);
      bool keepmin = (((lane & j) == 0) == ((lane & k) == 0));
      bool omin = o < key;
      key = (omin == keepmin) ? o : key;
    }
  }
  return key;
}
__device__ __forceinline__ unsigned long long bmerge64(unsigned long long key, int lane) {
#pragma unroll
  for (int j = 32; j > 0; j >>= 1) {
    unsigned long long o = __shfl_xor(key, j, 64);
    bool keepmin = ((lane & j) == 0);
    bool omin = o < key;
    key = (omin == keepmin) ? o : key;
  }
  return key;
}

// ---------------- mega: knn (0..2047) | dc (2048) | MLP chains (2049..3072) ----
// LDS: knn needs 8224 B, chain needs 16384 B (psconv runs in two 128-col halves)
#define MEGA_GRID 3073
__global__ __launch_bounds__(256) void k_mega(const float4* __restrict__ c4,
                                              int* __restrict__ idxo, float* __restrict__ wo,
                                              const float* __restrict__ cloud,
                                              const float* __restrict__ tvec,
                                              float* __restrict__ dc,
                                              const float* __restrict__ pconv1_w, const float* __restrict__ pconv1_b,
                                              const float* __restrict__ pconv2_b, const float* __restrict__ psconv1_b,
                                              const float* __restrict__ psconv2_b,
                                              const unsigned short* __restrict__ feat_h,
                                              const unsigned short* __restrict__ feat_l,
                                              const float* __restrict__ conv1_b, const float* __restrict__ conv2_b,
                                              const unsigned short* __restrict__ Wh,
                                              const unsigned short* __restrict__ Wl,
                                              float* __restrict__ pf, float* __restrict__ Yfp,
                                              float* __restrict__ Yf) {
  __shared__ __align__(16) char smem[16384];
  int tid = threadIdx.x, lane = tid & 63, w = tid >> 6;
  int mr = lane & 15, q = lane >> 4;
  if (blockIdx.x > 2048) {
    unsigned short* sh_h = (unsigned short*)smem;            // [0,4096) shorts: A @0..2048, B @2048..4096
    unsigned short* sh_l = (unsigned short*)(smem + 8192);
    int cb = blockIdx.x - 2049;
    if (cb < 512) {
      int m0 = cb * 16;
      // stage 1: pconv1 (K=3) directly in A-frag ownership
      float4 cp = c4[m0 + mr];
      short8 ah0, al0, ah1, al1;
#pragma unroll
      for (int j = 0; j < 8; ++j) {
        int c0 = q*8 + j, c1 = 32 + q*8 + j;
        float v0 = lrelu(fmaf(cp.x, pconv1_w[c0*3+0], fmaf(cp.y, pconv1_w[c0*3+1],
                          fmaf(cp.z, pconv1_w[c0*3+2], pconv1_b[c0]))));
        float v1 = lrelu(fmaf(cp.x, pconv1_w[c1*3+0], fmaf(cp.y, pconv1_w[c1*3+1],
                          fmaf(cp.z, pconv1_w[c1*3+2], pconv1_b[c1]))));
        unsigned short hh, ll;
        split2(v0, hh, ll); ah0[j] = (short)hh; al0[j] = (short)ll;
        split2(v1, hh, ll); ah1[j] = (short)hh; al1[j] = (short)ll;
      }
      // stage 2: pconv2 (K=64, N=128) -> region A
      f32x4 acc[2];
#pragma unroll
      for (int t = 0; t < 2; ++t) { f32x4 z = {0.f,0.f,0.f,0.f}; acc[t] = z; }
      const unsigned short* W2h = Wh + OFF_PCONV2;
      const unsigned short* W2l = Wl + OFF_PCONV2;
#pragma unroll
      for (int tt = 0; tt < 2; ++tt) {
        int t1 = 2*w + tt;
        int w0 = ((t1*2 + 0)*64 + lane)*8, w1 = ((t1*2 + 1)*64 + lane)*8;
        mfma3(acc[tt], ah0, al0, *(const short8*)(W2h + w0), *(const short8*)(W2l + w0));
        mfma3(acc[tt], ah1, al1, *(const short8*)(W2h + w1), *(const short8*)(W2l + w1));
      }
#pragma unroll
      for (int tt = 0; tt < 2; ++tt) {
        int t1 = 2*w + tt, n = t1*16 + mr;
        float b = pconv2_b[n];
        int ks2 = t1 >> 1, q2 = (t1 & 1)*2 + (mr >> 3), jd = mr & 7;
#pragma unroll
        for (int r = 0; r < 4; ++r) {
          int row = q*4 + r;
          float v = acc[tt][r] + b;
          pf[(size_t)(m0+row)*128 + n] = v;
          unsigned short hh, ll; split2(v, hh, ll);
          int p = ((ks2*16 + row)*4 + q2)*8 + jd;
          sh_h[p] = hh; sh_l[p] = ll;
        }
      }
      __syncthreads();
      // stages 3+4: psconv1/psconv2 in two 128-col halves (acc3 persists)
      f32x4 acc3[2];
#pragma unroll
      for (int t = 0; t < 2; ++t) { f32x4 z = {0.f,0.f,0.f,0.f}; acc3[t] = z; }
      const unsigned short* W3h = Wh + OFF_PSCONV1;
      const unsigned short* W3l = Wl + OFF_PSCONV1;
      const unsigned short* W4h = Wh + OFF_PSCONV2;
      const unsigned short* W4l = Wl + OFF_PSCONV2;
#pragma unroll
      for (int h = 0; h < 2; ++h) {
        f32x4 acc2[2];
#pragma unroll
        for (int t = 0; t < 2; ++t) { f32x4 z = {0.f,0.f,0.f,0.f}; acc2[t] = z; }
#pragma unroll
        for (int ks = 0; ks < 4; ++ks) {
          int ap = ((ks*16 + mr)*4 + q)*8;
          short8 ah = *(const short8*)&sh_h[ap];
          short8 al = *(const short8*)&sh_l[ap];
#pragma unroll
          for (int tt = 0; tt < 2; ++tt) {
            int ts = h*8 + 2*w + tt;
            int wb = ((ts*4 + ks)*64 + lane)*8;
            mfma3(acc2[tt], ah, al, *(const short8*)(W3h + wb), *(const short8*)(W3l + wb));
          }
        }
#pragma unroll
        for (int tt = 0; tt < 2; ++tt) {
          int tl = 2*w + tt;
          int n = h*128 + tl*16 + mr;
          float b = psconv1_b[n];
          int ks3 = tl >> 1, q3 = (tl & 1)*2 + (mr >> 3), jd = mr & 7;
#pragma unroll
          for (int r = 0; r < 4; ++r) {
            int row = q*4 + r;
            float v = lrelu(acc2[tt][r] + b);
            unsigned short hh, ll; split2(v, hh, ll);
            int p = 2048 + ((ks3*16 + row)*4 + q3)*8 + jd;
            sh_h[p] = hh; sh_l[p] = ll;
          }
        }
        __syncthreads();
#pragma unroll
        for (int ks = 0; ks < 4; ++ks) {
          int ap = 2048 + ((ks*16 + mr)*4 + q)*8;
          short8 ah = *(const short8*)&sh_h[ap];
          short8 al = *(const short8*)&sh_l[ap];
#pragma unroll
          for (int tt = 0; tt < 2; ++tt) {
            int wb = (((2*w+tt)*8 + h*4 + ks)*64 + lane)*8;
            mfma3(acc3[tt], ah, al, *(const short8*)(W4h + wb), *(const short8*)(W4l + wb));
          }
        }
        __syncthreads();
      }
#pragma unroll
      for (int tt = 0; tt < 2; ++tt) {
        int n = (2*w+tt)*16 + mr;
        float b = psconv2_b[n];
#pragma unroll
        for (int r = 0; r < 4; ++r)
          Yfp[(size_t)(m0 + q*4 + r)*128 + n] = acc3[tt][r] + b;
      }
    } else {
      int m0 = (cb - 512) * 16;
      int ab = ((m0 >> 4)*64 + lane)*8;
      short8 ah = *(const short8*)(feat_h + ab);
      short8 al = *(const short8*)(feat_l + ab);
      f32x4 acc = {0.f,0.f,0.f,0.f};
      const unsigned short* W1h = Wh + OFF_CONV1;
      const unsigned short* W1l = Wl + OFF_CONV1;
      {
        int wb = (w*64 + lane)*8;
        mfma3(acc, ah, al, *(const short8*)(W1h + wb), *(const short8*)(W1l + wb));
      }
      {
        int n = w*16 + mr;
        float b = conv1_b[n];
        int ks2 = n >> 5, q2 = (n >> 3) & 3, jd = mr & 7;
#pragma unroll
        for (int r = 0; r < 4; ++r) {
          int row = q*4 + r;
          float v = lrelu(acc[r] + b);
          unsigned short hh, ll; split2(v, hh, ll);
          int p = ((ks2*16 + row)*4 + q2)*8 + jd;
          sh_h[p] = hh; sh_l[p] = ll;
        }
      }
      __syncthreads();
      f32x4 acc2[2];
#pragma unroll
      for (int t = 0; t < 2; ++t) { f32x4 z = {0.f,0.f,0.f,0.f}; acc2[t] = z; }
      const unsigned short* W2h = Wh + OFF_CONV2;
      const unsigned short* W2l = Wl + OFF_CONV2;
#pragma unroll
      for (int ks = 0; ks < 2; ++ks) {
        int ap = ((ks*16 + mr)*4 + q)*8;
        short8 a2 = *(const short8*)&sh_h[ap];
        short8 a2l = *(const short8*)&sh_l[ap];
#pragma unroll
        for (int tt = 0; tt < 2; ++tt) {
          int wb = (((2*w+tt)*2 + ks)*64 + lane)*8;
          mfma3(acc2[tt], a2, a2l, *(const short8*)(W2h + wb), *(const short8*)(W2l + wb));
        }
      }
#pragma unroll
      for (int tt = 0; tt < 2; ++tt) {
        int n = (2*w+tt)*16 + mr;
        float b = conv2_b[n];
#pragma unroll
        for (int r = 0; r < 4; ++r)
          Yf[(size_t)(m0 + q*4 + r)*128 + n] = acc2[tt][r] + b;
      }
    }
    return;
  }
  if (blockIdx.x == 2048) {
    float* sred = (float*)smem;
    float tx = tvec[0], ty = tvec[1], tz = tvec[2];
    float v[32];
    float m = -INFINITY;
#pragma unroll
    for (int i2 = 0; i2 < 32; ++i2) {
      int n = i2*256 + tid;
      float ax = cloud[n*3+0] + tx, ay = cloud[n*3+1] + ty, az = cloud[n*3+2] + tz;
      v[i2] = sqrtf(ax*ax + ay*ay + az*az);
      m = fmaxf(m, v[i2]);
    }
#pragma unroll
    for (int o = 1; o < 64; o <<= 1) m = fmaxf(m, __shfl_xor(m, o, 64));
    if (lane == 0) sred[w] = m;
    __syncthreads();
    m = fmaxf(fmaxf(sred[0], sred[1]), fmaxf(sred[2], sred[3]));
    __syncthreads();
    float s = 0.f;
#pragma unroll
    for (int i2 = 0; i2 < 32; ++i2) { v[i2] = expf(v[i2] - m); s += v[i2]; }
#pragma unroll
    for (int o = 1; o < 64; o <<= 1) s += __shfl_xor(s, o, 64);
    if (lane == 0) sred[w] = s;
    __syncthreads();
    s = sred[0] + sred[1] + sred[2] + sred[3];
#pragma unroll
    for (int i2 = 0; i2 < 32; ++i2) dc[i2*256 + tid] = v[i2] / s;
    return;
  }
  // knn
  float (*smin)[256] = (float(*)[256])smem;                 // 4096 B
  float* sTv = (float*)(smem + 4096);                       // 16 B
  int*   scnt = (int*)(smem + 4112);                        // 16 B
  float (*sd)[KCAP] = (float(*)[KCAP])(smem + 4128);        // 2048 B
  int   (*sj)[KCAP] = (int(*)[KCAP])(smem + 6176);          // 2048 B
  int q0 = blockIdx.x * 4;
  float4 p0 = c4[q0], p1 = c4[q0+1], p2 = c4[q0+2], p3 = c4[q0+3];
  float p0x = -2.f*p0.x, p0y = -2.f*p0.y, p0z = -2.f*p0.z;
  float p1x = -2.f*p1.x, p1y = -2.f*p1.y, p1z = -2.f*p1.z;
  float p2x = -2.f*p2.x, p2y = -2.f*p2.y, p2z = -2.f*p2.z;
  float p3x = -2.f*p3.x, p3y = -2.f*p3.y, p3z = -2.f*p3.z;
#define DDOT(PX,PY,PZ,PW,CJ) fmaf(PX,(CJ).x, fmaf(PY,(CJ).y, fmaf(PZ,(CJ).z, PW + (CJ).w)))
  float m0 = INFINITY, m1 = INFINITY, m2 = INFINITY, m3 = INFINITY;
  for (int t = 0; t < 32; ++t) {
    float4 cj = c4[t*256 + tid];
    m0 = fminf(m0, DDOT(p0x,p0y,p0z,p0.w,cj));
    m1 = fminf(m1, DDOT(p1x,p1y,p1z,p1.w,cj));
    m2 = fminf(m2, DDOT(p2x,p2y,p2z,p2.w,cj));
    m3 = fminf(m3, DDOT(p3x,p3y,p3z,p3.w,cj));
  }
  smin[0][tid] = m0; smin[1][tid] = m1; smin[2][tid] = m2; smin[3][tid] = m3;
  if (tid < 4) scnt[tid] = 0;
  __syncthreads();
  {
    float4 vv = *(const float4*)&smin[w][lane*4];
    float m4 = fmaxf(fminf(fminf(vv.x, vv.y), fminf(vv.z, vv.w)), 0.f);
    unsigned key = bsort32u(__float_as_uint(m4), lane);
    float T = __uint_as_float(__shfl(key, 31, 64));
    if (lane == 0) sTv[w] = T * (1.f + 2e-5f) + 4e-5f;
  }
  __syncthreads();
  float T0 = sTv[0], T1 = sTv[1], T2 = sTv[2], T3 = sTv[3];
  for (int t = 0; t < 32; ++t) {
    int j = t*256 + tid;
    float4 cj = c4[j];
    float d;
#define APPEND(Q, P) { \
    float dx_ = (P).x-cj.x, dy_ = (P).y-cj.y, dz_ = (P).z-cj.z; \
    float de_ = dx_*dx_ + dy_*dy_ + dz_*dz_; \
    int p_ = atomicAdd(&scnt[Q],1); if (p_ < KCAP) { sd[Q][p_] = de_; sj[Q][p_] = j; } }
    d = DDOT(p0x,p0y,p0z,p0.w,cj); if (d <= T0) APPEND(0, p0);
    d = DDOT(p1x,p1y,p1z,p1.w,cj); if (d <= T1) APPEND(1, p1);
    d = DDOT(p2x,p2y,p2z,p2.w,cj); if (d <= T2) APPEND(2, p2);
    d = DDOT(p3x,p3y,p3z,p3.w,cj); if (d <= T3) APPEND(3, p3);
  }
  __syncthreads();
  int M = scnt[w]; if (M > KCAP) M = KCAP;
  unsigned long long key = (lane < M)
      ? (((unsigned long long)__float_as_uint(sd[w][lane]) << 32) | (unsigned)sj[w][lane])
      : ~0ull;
  key = bsort64(key, lane);
  for (int base = 64; base < M; base += 64) {
    unsigned long long nk = (base + lane < M)
        ? (((unsigned long long)__float_as_uint(sd[w][base+lane]) << 32) | (unsigned)sj[w][base+lane])
        : ~0ull;
    nk = bsort64(nk, lane);
    nk = __shfl_xor(nk, 63, 64);
    key = key < nk ? key : nk;
    key = bmerge64(key, lane);
  }
  float dsel = __uint_as_float((unsigned)(key >> 32));
  int   jsel = (int)(unsigned)(key & 0xffffffffu);
  float v = -sqrtf(dsel);
  float mx = v;
#pragma unroll
  for (int o = 1; o < 32; o <<= 1) mx = fmaxf(mx, __shfl_xor(mx, o, 64));
  float e = expf(v - mx);
  float s = e;
#pragma unroll
  for (int o = 1; o < 32; o <<= 1) s += __shfl_xor(s, o, 64);
  if (lane < 32) {
    int qd = q0 + w;
    wo[qd*32 + lane] = e / s;
    idxo[qd*32 + lane] = jsel;
  }
}

// ---------------- tail: pool(18 rows) + final GEMM + conv3 + head, one kernel --
// LDS fin: plane stride 18720 B (13 ks x 18 rows x 80 B padded chunks).
// Overlay after final GEMM: fused planes (stride 5760), t1 planes (@11520,
// stride 5120), shead (@21760).
__global__ __launch_bounds__(256) void k_tail(const float* __restrict__ Yf,
                                              const float* __restrict__ Yfp,
                                              const float* __restrict__ feat,
                                              const float* __restrict__ pf,
                                              const int* __restrict__ idx,
                                              const float* __restrict__ wsm,
                                              const unsigned short* __restrict__ Wh,
                                              const unsigned short* __restrict__ Wl,
                                              const float* __restrict__ final_b,
                                              const float* __restrict__ biasc,
                                              const float* __restrict__ bias2c,
                                              const float* __restrict__ segw, const float* __restrict__ segb,
                                              const float* __restrict__ disw, const float* __restrict__ disb,
                                              unsigned short* __restrict__ fusedh,
                                              unsigned short* __restrict__ fusedl,
                                              float* __restrict__ osegp, float* __restrict__ odisp) {
  __shared__ int sjn[18][32];
  __shared__ float swn[18][32];
  __shared__ __align__(16) char sbuf[37440];
  int tid = threadIdx.x, lane = tid & 63, w = tid >> 6;
  int mr = lane & 15, q = lane >> 4;
  int mt = blockIdx.x, m0 = mt * 16;
  // P1: neighbor lists for 18 rows (halo +-1)
  for (int t = tid; t < 18*32; t += 256) {
    int lr = t >> 5, k = t & 31, gr = m0 - 1 + lr;
    if (gr >= 0 && gr < NPT) { sjn[lr][k] = idx[gr*32+k]; swn[lr][k] = wsm[gr*32+k]; }
    else { sjn[lr][k] = 0; swn[lr][k] = 0.f; }
  }
  __syncthreads();
  // P2: build fin[18][416] split planes in LDS (1872 items of 4 channels)
  for (int t = tid; t < 1872; t += 256) {
    int lr, col;
    float4 v4;
    if (t < 1152) {
      lr = t >> 6; int arr = (t >> 5) & 1, cg = t & 31;
      const float* Y = arr ? Yf : Yfp;
      float ax = -INFINITY, ay = -INFINITY, az = -INFINITY, aw = -INFINITY;
#pragma unroll 8
      for (int k = 0; k < 32; ++k) {
        float4 vv = *(const float4*)&Y[(size_t)sjn[lr][k]*128 + cg*4];
        float wk = swn[lr][k];
        ax = fmaxf(ax, wk*vv.x); ay = fmaxf(ay, wk*vv.y);
        az = fmaxf(az, wk*vv.z); aw = fmaxf(aw, wk*vv.w);
      }
      v4.x = lrelu(ax); v4.y = lrelu(ay); v4.z = lrelu(az); v4.w = lrelu(aw);
      col = (arr ? 160 : 0) + cg*4;
    } else if (t < 1728) {
      int u = t - 1152; lr = u >> 5; int cg = u & 31;
      int gr = m0 - 1 + lr;
      int gc = gr < 0 ? 0 : (gr >= NPT ? NPT-1 : gr);
      float4 p4 = *(const float4*)&pf[(size_t)gc*128 + cg*4];
      v4.x = lrelu(p4.x); v4.y = lrelu(p4.y); v4.z = lrelu(p4.z); v4.w = lrelu(p4.w);
      col = 288 + cg*4;
    } else {
      int u = t - 1728; lr = u >> 3; int cg = u & 7;
      int gr = m0 - 1 + lr;
      int gc = gr < 0 ? 0 : (gr >= NPT ? NPT-1 : gr);
      float4 p4 = *(const float4*)&feat[(size_t)gc*32 + cg*4];
      v4.x = lrelu(p4.x); v4.y = lrelu(p4.y); v4.z = lrelu(p4.z); v4.w = lrelu(p4.w);
      col = 128 + cg*4;
    }
    int gr = m0 - 1 + lr;
    if (gr < 0 || gr >= NPT) { v4.x = 0.f; v4.y = 0.f; v4.z = 0.f; v4.w = 0.f; }
    int ks = col >> 5, qq = (col >> 3) & 3, j0 = col & 7;
    char* base = sbuf + (ks*18 + lr)*80 + qq*16 + j0*2;
    short4v hv, lv;
    unsigned short hh, ll;
    split2(v4.x, hh, ll); hv[0] = (short)hh; lv[0] = (short)ll;
    split2(v4.y, hh, ll); hv[1] = (short)hh; lv[1] = (short)ll;
    split2(v4.z, hh, ll); hv[2] = (short)hh; lv[2] = (short)ll;
    split2(v4.w, hh, ll); hv[3] = (short)hh; lv[3] = (short)ll;
    *(short4v*)base = hv;
    *(short4v*)(base + 18720) = lv;
  }
  __syncthreads();
  // P3: final GEMM (K=416) on 2 m-tiles (rows 0..15 and 16..17+clamp)
  f32x4 accA[2], accB[2];
#pragma unroll
  for (int t = 0; t < 2; ++t) {
    f32x4 z = {0.f,0.f,0.f,0.f}; accA[t] = z; accB[t] = z;
  }
  const unsigned short* WFh = Wh + OFF_FINAL;
  const unsigned short* WFl = Wl + OFF_FINAL;
#pragma unroll
  for (int ks = 0; ks < 13; ++ks) {
    int arB = 16 + mr; if (arB > 17) arB = 17;
    const char* pA = sbuf + (ks*18 + mr)*80 + q*16;
    const char* pB = sbuf + (ks*18 + arB)*80 + q*16;
    short8 ahA = *(const short8*)pA;
    short8 alA = *(const short8*)(pA + 18720);
    short8 ahB = *(const short8*)pB;
    short8 alB = *(const short8*)(pB + 18720);
#pragma unroll
    for (int tt = 0; tt < 2; ++tt) {
      int wb = (((2*w+tt)*13 + ks)*64 + lane)*8;
      short8 wh = *(const short8*)(WFh + wb);
      short8 wl = *(const short8*)(WFl + wb);
      mfma3(accA[tt], ahA, alA, wh, wl);
      mfma3(accB[tt], ahB, alB, wh, wl);
    }
  }
  __syncthreads();   // all fin reads done; overlay region now writable
  // P3b: write fused split planes to LDS overlay (zero OOB rows = conv zero-pad)
#pragma unroll
  for (int tile = 0; tile < 2; ++tile) {
#pragma unroll
    for (int tt = 0; tt < 2; ++tt) {
      int t2 = 2*w + tt, n = t2*16 + mr;
      float b = final_b[n];
      int ksA = t2 >> 1, qq = (t2 & 1)*2 + (mr >> 3), jd = mr & 7;
#pragma unroll
      for (int r = 0; r < 4; ++r) {
        int lr = tile*16 + q*4 + r;
        if (lr > 17) continue;
        int gr = m0 - 1 + lr;
        float v = (tile ? accB[tt][r] : accA[tt][r]) + b;
        if (gr < 0 || gr >= NPT) v = 0.f;
        unsigned short hh, ll; split2(v, hh, ll);
        char* p = sbuf + (ksA*18 + lr)*80 + qq*16 + jd*2;
        *(unsigned short*)p = hh;
        *(unsigned short*)(p + 5760) = ll;
      }
    }
  }
  __syncthreads();
  // P3c: write global fused chunks (main 16 rows) for the g-reduction kernel
  {
    int ks2 = tid >> 6, q2 = (tid >> 4) & 3, mr2 = tid & 15;
    int lr = mr2 + 1;
    const char* p = sbuf + (ks2*18 + lr)*80 + q2*16;
    short8 oh = *(const short8*)p;
    short8 ol = *(const short8*)(p + 5760);
    size_t pos = ((size_t)mt*256 + tid)*8;
    *(short8*)(fusedh + pos) = oh;
    *(short8*)(fusedl + pos) = ol;
  }
  // P4: conv3 (K=384 via taps) from local fused (halo resident, no bounds check)
  f32x4 acc3[2];
#pragma unroll
  for (int t = 0; t < 2; ++t) { f32x4 z = {0.f,0.f,0.f,0.f}; acc3[t] = z; }
  const unsigned short* W3h = Wh + OFF_W3;
  const unsigned short* W3l = Wl + OFF_W3;
#pragma unroll
  for (int ks = 0; ks < 12; ++ks) {
    int tap = ks >> 2, ksA = ks & 3;
    int ar = mr + tap;                     // local fused row 0..17
    const char* p = sbuf + (ksA*18 + ar)*80 + q*16;
    short8 ah = *(const short8*)p;
    short8 al = *(const short8*)(p + 5760);
#pragma unroll
    for (int tt = 0; tt < 2; ++tt) {
      int wb = (((2*w+tt)*12 + ks)*64 + lane)*8;
      mfma3(acc3[tt], ah, al, *(const short8*)(W3h + wb), *(const short8*)(W3l + wb));
    }
  }
#pragma unroll
  for (int tt = 0; tt < 2; ++tt) {
    int t2 = 2*w + tt, n = t2*16 + mr;
    float b = biasc[n];
    int ks2 = t2 >> 1, q2 = (t2 & 1)*2 + (mr >> 3), jd = mr & 7;
#pragma unroll
    for (int r = 0; r < 4; ++r) {
      int row = q*4 + r;
      float v = lrelu(acc3[tt][r] + b);
      unsigned short hh, ll; split2(v, hh, ll);
      char* p = sbuf + 11520 + (ks2*16 + row)*80 + q2*16 + jd*2;
      *(unsigned short*)p = hh;
      *(unsigned short*)(p + 5120) = ll;
    }
  }
  __syncthreads();
  // P5: head GEMM (K=128, block-diag seg2|dis2) + fused 1-wide heads
  f32x4 acc4 = {0.f,0.f,0.f,0.f};
  const unsigned short* WPh = Wh + OFF_W2P;
  const unsigned short* WPl = Wl + OFF_W2P;
#pragma unroll
  for (int ks = 0; ks < 4; ++ks) {
    const char* p = sbuf + 11520 + (ks*16 + mr)*80 + q*16;
    short8 ah = *(const short8*)p;
    short8 al = *(const short8*)(p + 5120);
    int wb = ((w*4 + ks)*64 + lane)*8;
    mfma3(acc4, ah, al, *(const short8*)(WPh + wb), *(const short8*)(WPl + wb));
  }
  float hw = (w < 2) ? segw[w*16 + mr] : disw[(w-2)*16 + mr];
  float bb = bias2c[w*16 + mr];
  float* shead = (float*)(sbuf + 21760);   // [4][16][17]
#pragma unroll
  for (int r = 0; r < 4; ++r)
    shead[(w*16 + q*4 + r)*17 + mr] = lrelu(acc4[r] + bb) * hw;
  __syncthreads();
  if (tid < 16) {
    float a = 0.f;
#pragma unroll
    for (int i = 0; i < 16; ++i) a += shead[(tid)*17 + i] + shead[(16 + tid)*17 + i];
    osegp[m0 + tid] = a + segb[0];
  } else if (tid < 32) {
    int r2 = tid - 16;
    float a = 0.f;
#pragma unroll
    for (int i = 0; i < 16; ++i) a += shead[(32 + r2)*17 + i] + shead[(48 + r2)*17 + i];
    odisp[m0 + r2] = a + disb[0];
  }
}

// ---------------- gk: g = sum fused*dc*seg (32 blocks) + gated kp MLP ----------
__global__ __launch_bounds__(256) void k_gk(const unsigned short* __restrict__ Ah,
                                            const unsigned short* __restrict__ Al,
                                            const float* __restrict__ dc,
                                            const float* __restrict__ seg,
                                            float* __restrict__ g,
                                            const float* __restrict__ l1w, const float* __restrict__ l1b,
                                            const float* __restrict__ l2w, const float* __restrict__ l2b,
                                            const float* __restrict__ l3w, const float* __restrict__ l3b,
                                            float* __restrict__ o_kp) {
  __shared__ float sred[2048];
  __shared__ int slast;
  int tid = threadIdx.x;
  int b = blockIdx.x;
  float pg[8] = {0.f,0.f,0.f,0.f,0.f,0.f,0.f,0.f};
  int mrr = tid & 15;
  for (int mi = 0; mi < 16; ++mi) {
    int m = b*16 + mi;
    int row = m*16 + mrr;
    float wrow = dc[row] * seg[row];
    size_t pos = ((size_t)m*256 + tid)*8;
    short8 hv = *(const short8*)(Ah + pos);
    short8 lv = *(const short8*)(Al + pos);
#pragma unroll
    for (int j = 0; j < 8; ++j)
      pg[j] += (bf2f((unsigned short)hv[j]) + bf2f((unsigned short)lv[j])) * wrow;
  }
#pragma unroll
  for (int j = 0; j < 8; ++j) sred[tid*8 + j] = pg[j];
  __syncthreads();
  if (tid < 128) {
    int ks = tid >> 5, q2 = (tid >> 3) & 3, j = tid & 7;
    float s = 0.f;
#pragma unroll
    for (int mr2 = 0; mr2 < 16; ++mr2) s += sred[((ks<<6) + (q2<<4) + mr2)*8 + j];
    atomicAdd(&g[tid], s);
  }
  __threadfence();
  __syncthreads();
  if (tid == 0) slast = (atomicAdd((int*)(g + 128), 1) == 31);
  __syncthreads();
  if (!slast) return;
  __shared__ float sg[128], s1[90], s2[64];
  if (tid < 128) sg[tid] = atomicAdd(&g[tid], 0.f);
  __syncthreads();
  if (tid < 90) {
    float a = l1b[tid];
    for (int i = 0; i < 128; ++i) a += sg[i]*l1w[tid*128+i];
    s1[tid] = lrelu(a);
  }
  __syncthreads();
  if (tid < 64) {
    float a = l2b[tid];
    for (int i = 0; i < 90; ++i) a += s1[i]*l2w[tid*90+i];
    s2[tid] = lrelu(a);
  }
  __syncthreads();
  if (tid < 24) {
    float a = l3b[tid];
    for (int i = 0; i < 64; ++i) a += s2[i]*l3w[tid*64+i];
    o_kp[tid] = a;
  }
}

extern "C" void kernel_launch(void* const* d_in, const int* in_sizes, int n_in,
                              void* d_out, int out_size, void* d_ws, size_t ws_size,
                              hipStream_t stream) {
  const float* seg      = (const float*)d_in[0];
  const float* img      = (const float*)d_in[1];
  const float* cloud    = (const float*)d_in[2];
  const float* tvec     = (const float*)d_in[3];
  const int*   choose   = (const int*)d_in[4];
  const float* pconv1_w = (const float*)d_in[5];
  const float* pconv1_b = (const float*)d_in[6];
  const float* pconv2_w = (const float*)d_in[7];
  const float* pconv2_b = (const float*)d_in[8];
  const float* conv1_w  = (const float*)d_in[9];
  const float* conv1_b  = (const float*)d_in[10];
  const float* conv2_w  = (const float*)d_in[11];
  const float* conv2_b  = (const float*)d_in[12];
  const float* psconv1_w= (const float*)d_in[13];
  const float* psconv1_b= (const float*)d_in[14];
  const float* psconv2_w= (const float*)d_in[15];
  const float* psconv2_b= (const float*)d_in[16];
  const float* final_w  = (const float*)d_in[17];
  const float* final_b  = (const float*)d_in[18];
  const float* seg1_w   = (const float*)d_in[19];
  const float* seg1_b   = (const float*)d_in[20];
  const float* seg2_w   = (const float*)d_in[21];
  const float* seg2_b   = (const float*)d_in[22];
  const float* seg3_w   = (const float*)d_in[23];
  const float* seg3_b   = (const float*)d_in[24];
  const float* dis1_w   = (const float*)d_in[25];
  const float* dis1_b   = (const float*)d_in[26];
  const float* dis2_w   = (const float*)d_in[27];
  const float* dis2_b   = (const float*)d_in[28];
  const float* dis3_w   = (const float*)d_in[29];
  const float* dis3_b   = (const float*)d_in[30];
  const float* lin1_w   = (const float*)d_in[31];
  const float* lin1_b   = (const float*)d_in[32];
  const float* lin2_w   = (const float*)d_in[33];
  const float* lin2_b   = (const float*)d_in[34];
  const float* lin3_w   = (const float*)d_in[35];
  const float* lin3_b   = (const float*)d_in[36];

  float* out = (float*)d_out;
  float* ws  = (float*)d_ws;

  // workspace layout (float offsets)
  float* c4     = ws + 0;          // 32768
  float* feat   = ws + 32768;      // 262144
  unsigned short* feat_h = (unsigned short*)(ws + 294912);   // 131072 f
  unsigned short* feat_l = (unsigned short*)(ws + 425984);   // 131072 f
  float* pf     = ws + 557056;     // 1048576
  float* Yf     = ws + 1605632;    // 1048576
  float* Yfp    = ws + 2654208;    // 1048576
  int*   idx    = (int*)(ws + 3702784);   // 262144
  float* wsm    = ws + 3964928;    // 262144
  unsigned short* fusedh = (unsigned short*)(ws + 8683520);  // 524288 f
  unsigned short* fusedl = (unsigned short*)(ws + 9207808);  // 524288 f
  unsigned short* Wh    = (unsigned short*)(ws + 9732096);   // 97280 f
  unsigned short* Wl    = (unsigned short*)(ws + 9829376);   // 97280 f
  float* biasc  = ws + 9926656;    // 128
  float* bias2c = ws + 9926784;    // 64
  float* g      = ws + 9926848;    // 129 (g[128] = block counter)

  float* o_kp   = out;             // 24
  float* o_disp = out + 24;        // 8192
  float* o_dc   = out + 8216;      // 8192
  float* o_segp = out + 16408;     // 8192

  k_prep<<<(PREP_TOTAL + 255)/256, 256, 0, stream>>>(
      cloud, choose, img, seg1_w, dis1_w, seg1_b, dis1_b,
      seg2_w, dis2_w, seg2_b, dis2_b,
      pconv2_w, conv1_w, conv2_w, psconv1_w, psconv2_w, final_w,
      c4, g, biasc, bias2c, feat, feat_h, feat_l, Wh, Wl);

  k_mega<<<MEGA_GRID, 256, 0, stream>>>(
      (const float4*)c4, idx, wsm, cloud, tvec, o_dc,
      pconv1_w, pconv1_b, pconv2_b, psconv1_b, psconv2_b,
      feat_h, feat_l, conv1_b, conv2_b, Wh, Wl, pf, Yfp, Yf);

  k_tail<<<512, 256, 0, stream>>>(
      Yf, Yfp, feat, pf, idx, wsm, Wh, Wl,
      final_b, biasc, bias2c, seg3_w, seg3_b, dis3_w, dis3_b,
      fusedh, fusedl, o_segp, o_disp);

  k_gk<<<32, 256, 0, stream>>>(fusedh, fusedl, o_dc, seg, g,
                               lin1_w, lin1_b, lin2_w, lin2_b, lin3_w, lin3_b, o_kp);

  (void)in_sizes; (void)n_in; (void)out_size; (void)ws_size;
}